// Round 4
// baseline (195.855 us; speedup 1.0000x reference)
//
#include <hip/hip_runtime.h>

#define NTOK 4096
#define CHAN 512
#define GSIZE 65536
#define RSQRT2 0.7071067811865476f
#define SCALE 0.17677669529663687f   // 1/sqrt(32)
#define WB_OFF 32768
#define QT_OFF (WB_OFF + 2097152)
#define WS_NEEDED ((size_t)(QT_OFF + 4194304))

typedef unsigned short ushort_t;
typedef __attribute__((ext_vector_type(8))) short bf16x8;
typedef __attribute__((ext_vector_type(8))) _Float16 f16x8;
typedef __attribute__((ext_vector_type(4))) float f32x4;

__device__ __forceinline__ ushort_t f2b(float f) {
    unsigned u = __float_as_uint(f);
    unsigned r = (u + 0x7FFFu + ((u >> 16) & 1u)) >> 16;
    return (ushort_t)r;
}
__device__ __forceinline__ unsigned pack2r(float a, float b) {
    unsigned ua = __float_as_uint(a), ub = __float_as_uint(b);
    return ((ua + 0x8000u) >> 16) | ((ub + 0x8000u) & 0xFFFF0000u);
}
__device__ __forceinline__ unsigned packh2(float a, float b) {
    return __builtin_bit_cast(unsigned, __builtin_amdgcn_cvt_pkrtz(a, b));
}
__device__ __forceinline__ ushort_t f2h(float f) {
    return (ushort_t)(packh2(f, f) & 0xFFFFu);
}
__device__ __forceinline__ bf16x8 ldfrag(const ushort_t* p) {
    return __builtin_bit_cast(bf16x8, *(const uint4*)p);
}
__device__ __forceinline__ f16x8 ldfragh(const ushort_t* p) {
    return __builtin_bit_cast(f16x8, *(const uint4*)p);
}

__global__ void diag_kernel(float* out, float v) {
    if (threadIdx.x == 0 && blockIdx.x == 0) out[0] = v;
}

// ---- GN pass A: per-channel sums. One block per channel (512 blocks).
__global__ __launch_bounds__(256) void gn_sums(const float* __restrict__ x,
                                               float* __restrict__ S,
                                               float* __restrict__ SS) {
    int c = blockIdx.x, t = threadIdx.x;
    const float4* p = (const float4*)(x + (size_t)c * 4096);
    float s = 0.f, ss = 0.f;
    #pragma unroll
    for (int i = 0; i < 4; i++) {
        float4 f = p[i * 256 + t];
        s += f.x + f.y + f.z + f.w;
        ss += f.x * f.x + f.y * f.y + f.z * f.z + f.w * f.w;
    }
    #pragma unroll
    for (int off = 32; off > 0; off >>= 1) {
        s += __shfl_xor(s, off);
        ss += __shfl_xor(ss, off);
    }
    __shared__ float as[4], bs[4];
    int w = t >> 6;
    if ((t & 63) == 0) { as[w] = s; bs[w] = ss; }
    __syncthreads();
    if (t == 0) {
        S[c] = as[0] + as[1] + as[2] + as[3];
        SS[c] = bs[0] + bs[1] + bs[2] + bs[3];
    }
}

// ---- GN pass B: coefficients. 1 block x 512 threads (thread = channel).
__global__ __launch_bounds__(512) void gn_coef(const float* __restrict__ S,
                                               const float* __restrict__ SS,
                                               const float* __restrict__ gnw,
                                               const float* __restrict__ gnb,
                                               float* __restrict__ qa,
                                               float* __restrict__ qd,
                                               float* __restrict__ va,
                                               float* __restrict__ vd) {
    int c = threadIdx.x;
    float Sc = S[c], SSc = SS[c];
    float gs = Sc, gss = SSc;
    #pragma unroll
    for (int off = 1; off < 16; off <<= 1) {
        gs += __shfl_xor(gs, off);
        gss += __shfl_xor(gss, off);
    }
    float mu = gs * (1.f / GSIZE);
    float var = gss * (1.f / GSIZE) - mu * mu;
    float r1 = rsqrtf(var + 1e-6f);
    float wc = gnw[c], bc = gnb[c];
    float a1 = r1 * wc;
    float d1 = bc - mu * a1;
    qa[c] = a1; qd[c] = d1;
    float S2 = a1 * Sc + 4096.f * d1;
    float SS2 = a1 * a1 * SSc + 2.f * a1 * d1 * Sc + 4096.f * d1 * d1;
    float gs2 = S2, gss2 = SS2;
    #pragma unroll
    for (int off = 1; off < 16; off <<= 1) {
        gs2 += __shfl_xor(gs2, off);
        gss2 += __shfl_xor(gss2, off);
    }
    float mu2 = gs2 * (1.f / GSIZE);
    float var2 = gss2 * (1.f / GSIZE) - mu2 * mu2;
    float r2 = rsqrtf(var2 + 1e-6f);
    float a2 = r2 * wc;
    va[c] = a1 * a2;
    vd[c] = a2 * (d1 - mu2) + bc;
}

// ---- Fold GN offsets into biases: b'[o] = b[o] + sum_c W[o][c]*d[c].
__global__ __launch_bounds__(256) void bias_fold(const float* __restrict__ wq,
                                                 const float* __restrict__ wk,
                                                 const float* __restrict__ wv,
                                                 const float* __restrict__ bq,
                                                 const float* __restrict__ bk,
                                                 const float* __restrict__ bv,
                                                 const float* __restrict__ qd,
                                                 const float* __restrict__ vd,
                                                 float* __restrict__ bqf,
                                                 float* __restrict__ bkf,
                                                 float* __restrict__ bvf) {
    int row = blockIdx.x * 4 + (threadIdx.x >> 6);   // 0..1535
    int lane = threadIdx.x & 63;
    int m = row >> 9;
    int o = row & 511;
    const float* W = (m == 0) ? wq : (m == 1) ? wk : wv;
    const float* b = (m == 0) ? bq : (m == 1) ? bk : bv;
    const float* d = (m == 0) ? qd : vd;
    float* outp    = (m == 0) ? bqf : (m == 1) ? bkf : bvf;
    const float4* wr = (const float4*)(W + (size_t)o * 512) + lane * 2;
    const float4* dr = (const float4*)d + lane * 2;
    float4 a0 = wr[0], a1 = wr[1], d0 = dr[0], d1 = dr[1];
    float acc = a0.x * d0.x + a0.y * d0.y + a0.z * d0.z + a0.w * d0.w
              + a1.x * d1.x + a1.y * d1.y + a1.z * d1.z + a1.w * d1.w;
    #pragma unroll
    for (int off = 32; off > 0; off >>= 1) acc += __shfl_xor(acc, off);
    if (lane == 0) outp[o] = b[o] + acc;
}

// ---- Weight prep: fp32 -> bf16 once, GN affine folded into wq/wk/wv.
__global__ __launch_bounds__(256) void wprep(const float* __restrict__ wq,
                                             const float* __restrict__ wk,
                                             const float* __restrict__ wv,
                                             const float* __restrict__ wo,
                                             const float* __restrict__ qa,
                                             const float* __restrict__ va,
                                             ushort_t* __restrict__ Wb) {
    int y = blockIdx.y;
    const float* src = (y == 0) ? wq : (y == 1) ? wk : (y == 2) ? wv : wo;
    int i = (blockIdx.x * 256 + threadIdx.x) * 4;
    float4 f = *(const float4*)(src + i);
    if (y < 3) {
        const float* aff = (y == 0) ? qa : va;
        float4 a = *(const float4*)(aff + (i & 511));
        f.x *= a.x; f.y *= a.y; f.z *= a.z; f.w *= a.w;
    }
    uint2 u;
    u.x = pack2r(f.x, f.y);
    u.y = pack2r(f.z, f.w);
    *(uint2*)(Wb + (size_t)y * 262144 + i) = u;
}

// ---- QKV projection. Tile 128m x 64n, K-step 64, grid (64, 12).
__global__ __launch_bounds__(256) void qkv_mfma(const float* __restrict__ x,
                                                const ushort_t* __restrict__ Wb,
                                                const float* __restrict__ bqf,
                                                const float* __restrict__ bkf,
                                                const float* __restrict__ bvf,
                                                ushort_t* __restrict__ QT,
                                                ushort_t* __restrict__ KT,
                                                ushort_t* __restrict__ Vb) {
    __shared__ __align__(16) ushort_t Wl[128][72];
    __shared__ __align__(16) ushort_t Bn[64][72];
    __shared__ __align__(16) ushort_t Tl[64][136];
    int t = threadIdx.x;
    int nbase = blockIdx.x << 6;
    int y = blockIdx.y;
    int buf = y >> 2;
    int obase = (y & 3) << 7;
    const ushort_t* Wsrc = Wb + (size_t)buf * 262144;
    const float* bias = (buf == 0) ? bqf : (buf == 1) ? bkf : bvf;

    int w = t >> 6, lane = t & 63, q15 = lane & 15, quad = lane >> 4;
    f32x4 acc[2][4];
    #pragma unroll
    for (int i = 0; i < 2; i++)
        #pragma unroll
        for (int j = 0; j < 4; j++) acc[i][j] = (f32x4){0.f, 0.f, 0.f, 0.f};

    int tok = t & 63, c8 = t >> 6;         // B staging roles
    for (int ck = 0; ck < 512; ck += 64) {
        __syncthreads();
        #pragma unroll
        for (int i = 0; i < 4; i++) {      // A: 1024 uint4 = 128 rows x 64 k
            int idx = 4 * t + i;
            int row = idx >> 3, seg = idx & 7;
            *(uint4*)&Wl[row][seg * 8] =
                *(const uint4*)&Wsrc[(size_t)(obase + row) * 512 + ck + seg * 8];
        }
        {   // B: 64 tok x 64 chans; lane = tok (coalesced), 16 chans each
            float v[16];
            #pragma unroll
            for (int i = 0; i < 16; i++)
                v[i] = x[(size_t)(ck + c8 * 16 + i) * NTOK + nbase + tok];
            uint4 u0, u1;
            u0.x = pack2r(v[0], v[1]);   u0.y = pack2r(v[2], v[3]);
            u0.z = pack2r(v[4], v[5]);   u0.w = pack2r(v[6], v[7]);
            u1.x = pack2r(v[8], v[9]);   u1.y = pack2r(v[10], v[11]);
            u1.z = pack2r(v[12], v[13]); u1.w = pack2r(v[14], v[15]);
            *(uint4*)&Bn[tok][c8 * 16] = u0;
            *(uint4*)&Bn[tok][c8 * 16 + 8] = u1;
        }
        __syncthreads();
        #pragma unroll
        for (int kk = 0; kk < 2; kk++) {
            bf16x8 af0 = ldfrag(&Wl[w * 32 + q15][kk * 32 + quad * 8]);
            bf16x8 af1 = ldfrag(&Wl[w * 32 + 16 + q15][kk * 32 + quad * 8]);
            #pragma unroll
            for (int n8 = 0; n8 < 4; n8++) {
                bf16x8 bfv = ldfrag(&Bn[n8 * 16 + q15][kk * 32 + quad * 8]);
                acc[0][n8] = __builtin_amdgcn_mfma_f32_16x16x32_bf16(af0, bfv, acc[0][n8], 0, 0, 0);
                acc[1][n8] = __builtin_amdgcn_mfma_f32_16x16x32_bf16(af1, bfv, acc[1][n8], 0, 0, 0);
            }
        }
    }

    if (buf == 2) {   // V: f16 [chan][tok]
        #pragma unroll
        for (int mi = 0; mi < 2; mi++)
            #pragma unroll
            for (int r = 0; r < 4; r++) {
                int o = obase + w * 32 + mi * 16 + quad * 4 + r;
                float bo = bias[o];
                #pragma unroll
                for (int n8 = 0; n8 < 4; n8++)
                    Vb[(size_t)o * NTOK + nbase + n8 * 16 + q15] = f2h(acc[mi][n8][r] + bo);
            }
        return;
    }

    // Q/K: transpose via Tl, full 1024-uint4 flush
    ushort_t* dstT = (buf == 0) ? QT : KT;
    float qs = (buf == 0) ? SCALE : 1.0f;
    __syncthreads();
    #pragma unroll
    for (int mi = 0; mi < 2; mi++)
        #pragma unroll
        for (int r = 0; r < 4; r++) {
            int mloc = w * 32 + mi * 16 + quad * 4 + r;
            float bo = bias[obase + mloc];
            #pragma unroll
            for (int n8 = 0; n8 < 4; n8++)
                Tl[n8 * 16 + q15][mloc] = f2b((acc[mi][n8][r] + bo) * qs);
        }
    __syncthreads();
    #pragma unroll
    for (int i = 0; i < 4; i++) {
        int idx = 4 * t + i;                // 1024 uint4: 64 rows x 16 segs
        int row = idx >> 4, ch = idx & 15;
        uint4 u = *(const uint4*)&Tl[row][ch * 8];
        *(uint4*)&dstT[(size_t)(nbase + row) * 512 + obase + ch * 8] = u;
    }
}

// ---- Attention v12: v11 (register-direct P via key permutation, 8 waves x
// 16 q) + double-buffered K/V LDS with async-stage split. One barrier per
// 256-key tile; next tile's global loads issue right after the barrier and
// their vmcnt wait lands at the ds_write AFTER compute, so L2 latency hides
// under the 4 h2 sub-passes. LDS 2x37376=74752 B — grid already caps at
// 2 blocks/CU, so doubling is free.
__global__ __launch_bounds__(512, 4) void attn_v12(ushort_t* __restrict__ QT,
                                                   const ushort_t* __restrict__ KT,
                                                   const ushort_t* __restrict__ V) {
    __shared__ __align__(16) ushort_t Kt[2][256][40];   // [buf][key(perm)][32 chans] bf16
    __shared__ __align__(16) ushort_t Vt[2][32][264];   // [buf][d][256 keys] f16
    int h = blockIdx.y;
    int t = threadIdx.x;
    int w = t >> 6, lane = t & 63, q15 = lane & 15, quad = lane >> 4;
    int qbase = (blockIdx.x << 7) + w * 16;             // wave-private 16 queries
    int hc = h * 32;
    const ushort_t* Vh = V + (size_t)hc * NTOK;

    bf16x8 qf = ldfrag(&QT[(size_t)(qbase + q15) * 512 + hc + quad * 8]);

    const uint4 onesu = {0x3C003C00u, 0x3C003C00u, 0x3C003C00u, 0x3C003C00u};
    const f16x8 ones = __builtin_bit_cast(f16x8, onesu);

    f32x4 o[2] = {{0.f, 0.f, 0.f, 0.f}, {0.f, 0.f, 0.f, 0.f}};
    f32x4 lacc = {0.f, 0.f, 0.f, 0.f};

    // staging geometry (per thread, fixed): K = 2 uint4, V = 2 uint4
    uint4 kreg[2], vreg[2];

    #define LOADT(J0)                                                           \
        {                                                                       \
            _Pragma("unroll")                                                   \
            for (int i = 0; i < 2; i++) {                                       \
                int idx = t + (i << 9);                                         \
                int krow = idx >> 2, kseg = idx & 3;                            \
                int rp = krow & 63;                                             \
                int src = (krow & 192) | (rp & 0x23) | ((rp & 0x0C) << 1) |     \
                          ((rp & 0x10) >> 2);                                   \
                kreg[i] = *(const uint4*)&KT[(size_t)((J0) + src) * 512 + hc +  \
                                             kseg * 8];                         \
            }                                                                   \
            _Pragma("unroll")                                                   \
            for (int i = 0; i < 2; i++) {                                       \
                int idx = t + (i << 9);                                         \
                int vrow = idx >> 5, vseg = idx & 31;                           \
                vreg[i] = *(const uint4*)&Vh[(size_t)vrow * NTOK + (J0) +       \
                                             vseg * 8];                         \
            }                                                                   \
        }

    #define STORET(B)                                                           \
        {                                                                       \
            _Pragma("unroll")                                                   \
            for (int i = 0; i < 2; i++) {                                       \
                int idx = t + (i << 9);                                         \
                *(uint4*)&Kt[(B)][idx >> 2][(idx & 3) * 8] = kreg[i];           \
            }                                                                   \
            _Pragma("unroll")                                                   \
            for (int i = 0; i < 2; i++) {                                       \
                int idx = t + (i << 9);                                         \
                *(uint4*)&Vt[(B)][idx >> 5][(idx & 31) * 8] = vreg[i];          \
            }                                                                   \
        }

    LOADT(0);
    STORET(0);

    #pragma unroll 2
    for (int tt = 0; tt < 16; tt++) {
        int cur = tt & 1;
        __syncthreads();                   // prev tile's ds_writes visible
        if (tt < 15) LOADT((tt + 1) << 8); // issue next tile loads (post-barrier)

        #pragma unroll
        for (int h2 = 0; h2 < 4; h2++) {   // four 64-key sub-passes
            f32x4 st[4];
            __builtin_amdgcn_s_setprio(1);
            #pragma unroll
            for (int kt = 0; kt < 4; kt++) {
                bf16x8 kf = ldfrag(&Kt[cur][h2 * 64 + kt * 16 + q15][quad * 8]);
                f32x4 z = {0.f, 0.f, 0.f, 0.f};
                st[kt] = __builtin_amdgcn_mfma_f32_16x16x32_bf16(kf, qf, z, 0, 0, 0);
            }
            __builtin_amdgcn_s_setprio(0);

            #pragma unroll
            for (int kt = 0; kt < 4; kt++)
                #pragma unroll
                for (int r = 0; r < 4; r++)
                    st[kt][r] = __expf(st[kt][r]);

            f16x8 v00 = ldfragh(&Vt[cur][q15][h2 * 64 + quad * 8]);
            f16x8 v01 = ldfragh(&Vt[cur][16 + q15][h2 * 64 + quad * 8]);
            f16x8 v10 = ldfragh(&Vt[cur][q15][h2 * 64 + 32 + quad * 8]);
            f16x8 v11 = ldfragh(&Vt[cur][16 + q15][h2 * 64 + 32 + quad * 8]);

            uint4 p0u, p1u;
            p0u.x = packh2(st[0][0], st[0][1]);
            p0u.y = packh2(st[0][2], st[0][3]);
            p0u.z = packh2(st[1][0], st[1][1]);
            p0u.w = packh2(st[1][2], st[1][3]);
            p1u.x = packh2(st[2][0], st[2][1]);
            p1u.y = packh2(st[2][2], st[2][3]);
            p1u.z = packh2(st[3][0], st[3][1]);
            p1u.w = packh2(st[3][2], st[3][3]);
            f16x8 pf0 = __builtin_bit_cast(f16x8, p0u);
            f16x8 pf1 = __builtin_bit_cast(f16x8, p1u);
            __builtin_amdgcn_s_setprio(1);
            o[0] = __builtin_amdgcn_mfma_f32_16x16x32_f16(pf0, v00, o[0], 0, 0, 0);
            o[1] = __builtin_amdgcn_mfma_f32_16x16x32_f16(pf0, v01, o[1], 0, 0, 0);
            lacc = __builtin_amdgcn_mfma_f32_16x16x32_f16(pf0, ones, lacc, 0, 0, 0);
            o[0] = __builtin_amdgcn_mfma_f32_16x16x32_f16(pf1, v10, o[0], 0, 0, 0);
            o[1] = __builtin_amdgcn_mfma_f32_16x16x32_f16(pf1, v11, o[1], 0, 0, 0);
            lacc = __builtin_amdgcn_mfma_f32_16x16x32_f16(pf1, ones, lacc, 0, 0, 0);
            __builtin_amdgcn_s_setprio(0);
        }

        if (tt < 15) STORET(cur ^ 1);      // vmcnt wait lands here, post-compute
    }
    #undef LOADT
    #undef STORET

    #pragma unroll
    for (int r = 0; r < 4; r++) {
        float li = 1.f / lacc[r];
        int q = quad * 4 + r;
        QT[(size_t)(qbase + q) * 512 + hc + q15]      = f2b(o[0][r] * li);
        QT[(size_t)(qbase + q) * 512 + hc + 16 + q15] = f2b(o[1][r] * li);
    }
}

// ---- Output projection: tile 64m x 64n, grid (64, 8). A = Wb[3] copy-staged.
__global__ __launch_bounds__(256) void oproj_mfma(const ushort_t* __restrict__ OT,
                                                  const ushort_t* __restrict__ Wob,
                                                  const float* __restrict__ bo,
                                                  const float* __restrict__ x,
                                                  float* __restrict__ out) {
    __shared__ __align__(16) ushort_t Wl[64][40];
    __shared__ __align__(16) ushort_t Bn[64][40];
    int t = threadIdx.x;
    int nbase = blockIdx.x << 6;
    int obase = blockIdx.y << 6;
    int w = t >> 6, lane = t & 63, q15 = lane & 15, quad = lane >> 4;

    f32x4 acc[4];
    #pragma unroll
    for (int i = 0; i < 4; i++) acc[i] = (f32x4){0.f, 0.f, 0.f, 0.f};

    int arow = t >> 2, aseg = t & 3;
    for (int ck = 0; ck < 512; ck += 32) {
        __syncthreads();
        *(uint4*)&Wl[arow][aseg * 8] =
            *(const uint4*)&Wob[(size_t)(obase + arow) * 512 + ck + aseg * 8];
        *(uint4*)&Bn[arow][aseg * 8] =
            *(const uint4*)&OT[(size_t)(nbase + arow) * 512 + ck + aseg * 8];
        __syncthreads();
        bf16x8 af = ldfrag(&Wl[w * 16 + q15][quad * 8]);
        #pragma unroll
        for (int n8 = 0; n8 < 4; n8++) {
            bf16x8 bfv = ldfrag(&Bn[n8 * 16 + q15][quad * 8]);
            acc[n8] = __builtin_amdgcn_mfma_f32_16x16x32_bf16(af, bfv, acc[n8], 0, 0, 0);
        }
    }

    #pragma unroll
    for (int r = 0; r < 4; r++) {
        int o = obase + w * 16 + quad * 4 + r;
        float b = bo[o];
        #pragma unroll
        for (int n8 = 0; n8 < 4; n8++) {
            size_t idx = (size_t)o * NTOK + nbase + n8 * 16 + q15;
            out[idx] = (acc[n8][r] + b + x[idx]) * RSQRT2;
        }
    }
}

extern "C" void kernel_launch(void* const* d_in, const int* in_sizes, int n_in,
                              void* d_out, int out_size, void* d_ws, size_t ws_size,
                              hipStream_t stream) {
    const float* x   = (const float*)d_in[0];
    const float* gnw = (const float*)d_in[1];
    const float* gnb = (const float*)d_in[2];
    const float* wq  = (const float*)d_in[3];
    const float* bq  = (const float*)d_in[4];
    const float* wk  = (const float*)d_in[5];
    const float* bk  = (const float*)d_in[6];
    const float* wv  = (const float*)d_in[7];
    const float* bv  = (const float*)d_in[8];
    const float* wo  = (const float*)d_in[9];
    const float* bo  = (const float*)d_in[10];
    float* out = (float*)d_out;

    if (ws_size < WS_NEEDED) {
        diag_kernel<<<1, 64, 0, stream>>>(out, (float)(ws_size >> 16));
        return;
    }

    char* wsb = (char*)d_ws;
    float* S   = (float*)(wsb + 0);
    float* SS  = (float*)(wsb + 2048);
    float* qa  = (float*)(wsb + 4096);
    float* qd  = (float*)(wsb + 6144);
    float* va  = (float*)(wsb + 8192);
    float* vd  = (float*)(wsb + 10240);
    float* bqf = (float*)(wsb + 12288);
    float* bkf = (float*)(wsb + 14336);
    float* bvf = (float*)(wsb + 16384);
    ushort_t* Wb = (ushort_t*)(wsb + WB_OFF);    // 2 MB bf16 (wq'|wk'|wv'|wo)
    ushort_t* QT = (ushort_t*)(wsb + QT_OFF);    // 4 MB bf16 [4096][512] (becomes O)
    ushort_t* KT = (ushort_t*)d_out;                        // 4 MB bf16 [4096][512]
    ushort_t* Vb = (ushort_t*)d_out + (size_t)CHAN * NTOK;  // 4 MB f16 [512][4096]

    gn_sums<<<512, 256, 0, stream>>>(x, S, SS);
    gn_coef<<<1, 512, 0, stream>>>(S, SS, gnw, gnb, qa, qd, va, vd);
    bias_fold<<<384, 256, 0, stream>>>(wq, wk, wv, bq, bk, bv, qd, vd, bqf, bkf, bvf);
    wprep<<<dim3(256, 4), 256, 0, stream>>>(wq, wk, wv, wo, qa, va, Wb);

    qkv_mfma<<<dim3(64, 12), 256, 0, stream>>>(x, Wb, bqf, bkf, bvf, QT, KT, Vb);

    attn_v12<<<dim3(32, 16), 512, 0, stream>>>(QT, KT, Vb);

    oproj_mfma<<<dim3(64, 8), 256, 0, stream>>>(QT, Wb + (size_t)3 * 262144, bo, x, out);
}

// Round 5
// 166.504 us; speedup vs baseline: 1.1763x; 1.1763x over previous
//
#include <hip/hip_runtime.h>

#define NTOK 4096
#define CHAN 512
#define GSIZE 65536
#define RSQRT2 0.7071067811865476f
#define SCALE 0.17677669529663687f   // 1/sqrt(32)
#define WB_OFF 32768
#define QT_OFF (WB_OFF + 2097152)
#define WS_NEEDED ((size_t)(QT_OFF + 4194304))

typedef unsigned short ushort_t;
typedef __attribute__((ext_vector_type(8))) short bf16x8;
typedef __attribute__((ext_vector_type(8))) _Float16 f16x8;
typedef __attribute__((ext_vector_type(4))) float f32x4;

__device__ __forceinline__ ushort_t f2b(float f) {
    unsigned u = __float_as_uint(f);
    unsigned r = (u + 0x7FFFu + ((u >> 16) & 1u)) >> 16;
    return (ushort_t)r;
}
__device__ __forceinline__ unsigned pack2r(float a, float b) {
    unsigned ua = __float_as_uint(a), ub = __float_as_uint(b);
    return ((ua + 0x8000u) >> 16) | ((ub + 0x8000u) & 0xFFFF0000u);
}
__device__ __forceinline__ unsigned packh2(float a, float b) {
    return __builtin_bit_cast(unsigned, __builtin_amdgcn_cvt_pkrtz(a, b));
}
__device__ __forceinline__ ushort_t f2h(float f) {
    return (ushort_t)(packh2(f, f) & 0xFFFFu);
}
__device__ __forceinline__ bf16x8 ldfrag(const ushort_t* p) {
    return __builtin_bit_cast(bf16x8, *(const uint4*)p);
}
__device__ __forceinline__ f16x8 ldfragh(const ushort_t* p) {
    return __builtin_bit_cast(f16x8, *(const uint4*)p);
}
// async global->LDS DMA, 16B per lane; LDS dest = wave-uniform base + lane*16
__device__ __forceinline__ void ldg2lds16(const void* g, void* l) {
    __builtin_amdgcn_global_load_lds(
        (const __attribute__((address_space(1))) void*)g,
        (__attribute__((address_space(3))) void*)l, 16, 0, 0);
}

__global__ void diag_kernel(float* out, float v) {
    if (threadIdx.x == 0 && blockIdx.x == 0) out[0] = v;
}

// ---- GN pass A: per-channel sums. One block per channel (512 blocks).
__global__ __launch_bounds__(256) void gn_sums(const float* __restrict__ x,
                                               float* __restrict__ S,
                                               float* __restrict__ SS) {
    int c = blockIdx.x, t = threadIdx.x;
    const float4* p = (const float4*)(x + (size_t)c * 4096);
    float s = 0.f, ss = 0.f;
    #pragma unroll
    for (int i = 0; i < 4; i++) {
        float4 f = p[i * 256 + t];
        s += f.x + f.y + f.z + f.w;
        ss += f.x * f.x + f.y * f.y + f.z * f.z + f.w * f.w;
    }
    #pragma unroll
    for (int off = 32; off > 0; off >>= 1) {
        s += __shfl_xor(s, off);
        ss += __shfl_xor(ss, off);
    }
    __shared__ float as[4], bs[4];
    int w = t >> 6;
    if ((t & 63) == 0) { as[w] = s; bs[w] = ss; }
    __syncthreads();
    if (t == 0) {
        S[c] = as[0] + as[1] + as[2] + as[3];
        SS[c] = bs[0] + bs[1] + bs[2] + bs[3];
    }
}

// ---- GN pass B: coefficients. 1 block x 512 threads (thread = channel).
__global__ __launch_bounds__(512) void gn_coef(const float* __restrict__ S,
                                               const float* __restrict__ SS,
                                               const float* __restrict__ gnw,
                                               const float* __restrict__ gnb,
                                               float* __restrict__ qa,
                                               float* __restrict__ qd,
                                               float* __restrict__ va,
                                               float* __restrict__ vd) {
    int c = threadIdx.x;
    float Sc = S[c], SSc = SS[c];
    float gs = Sc, gss = SSc;
    #pragma unroll
    for (int off = 1; off < 16; off <<= 1) {
        gs += __shfl_xor(gs, off);
        gss += __shfl_xor(gss, off);
    }
    float mu = gs * (1.f / GSIZE);
    float var = gss * (1.f / GSIZE) - mu * mu;
    float r1 = rsqrtf(var + 1e-6f);
    float wc = gnw[c], bc = gnb[c];
    float a1 = r1 * wc;
    float d1 = bc - mu * a1;
    qa[c] = a1; qd[c] = d1;
    float S2 = a1 * Sc + 4096.f * d1;
    float SS2 = a1 * a1 * SSc + 2.f * a1 * d1 * Sc + 4096.f * d1 * d1;
    float gs2 = S2, gss2 = SS2;
    #pragma unroll
    for (int off = 1; off < 16; off <<= 1) {
        gs2 += __shfl_xor(gs2, off);
        gss2 += __shfl_xor(gss2, off);
    }
    float mu2 = gs2 * (1.f / GSIZE);
    float var2 = gss2 * (1.f / GSIZE) - mu2 * mu2;
    float r2 = rsqrtf(var2 + 1e-6f);
    float a2 = r2 * wc;
    va[c] = a1 * a2;
    vd[c] = a2 * (d1 - mu2) + bc;
}

// ---- Fold GN offsets into biases: b'[o] = b[o] + sum_c W[o][c]*d[c].
__global__ __launch_bounds__(256) void bias_fold(const float* __restrict__ wq,
                                                 const float* __restrict__ wk,
                                                 const float* __restrict__ wv,
                                                 const float* __restrict__ bq,
                                                 const float* __restrict__ bk,
                                                 const float* __restrict__ bv,
                                                 const float* __restrict__ qd,
                                                 const float* __restrict__ vd,
                                                 float* __restrict__ bqf,
                                                 float* __restrict__ bkf,
                                                 float* __restrict__ bvf) {
    int row = blockIdx.x * 4 + (threadIdx.x >> 6);   // 0..1535
    int lane = threadIdx.x & 63;
    int m = row >> 9;
    int o = row & 511;
    const float* W = (m == 0) ? wq : (m == 1) ? wk : wv;
    const float* b = (m == 0) ? bq : (m == 1) ? bk : bv;
    const float* d = (m == 0) ? qd : vd;
    float* outp    = (m == 0) ? bqf : (m == 1) ? bkf : bvf;
    const float4* wr = (const float4*)(W + (size_t)o * 512) + lane * 2;
    const float4* dr = (const float4*)d + lane * 2;
    float4 a0 = wr[0], a1 = wr[1], d0 = dr[0], d1 = dr[1];
    float acc = a0.x * d0.x + a0.y * d0.y + a0.z * d0.z + a0.w * d0.w
              + a1.x * d1.x + a1.y * d1.y + a1.z * d1.z + a1.w * d1.w;
    #pragma unroll
    for (int off = 32; off > 0; off >>= 1) acc += __shfl_xor(acc, off);
    if (lane == 0) outp[o] = b[o] + acc;
}

// ---- Weight prep: fp32 -> bf16 once, GN affine folded into wq/wk/wv.
__global__ __launch_bounds__(256) void wprep(const float* __restrict__ wq,
                                             const float* __restrict__ wk,
                                             const float* __restrict__ wv,
                                             const float* __restrict__ wo,
                                             const float* __restrict__ qa,
                                             const float* __restrict__ va,
                                             ushort_t* __restrict__ Wb) {
    int y = blockIdx.y;
    const float* src = (y == 0) ? wq : (y == 1) ? wk : (y == 2) ? wv : wo;
    int i = (blockIdx.x * 256 + threadIdx.x) * 4;
    float4 f = *(const float4*)(src + i);
    if (y < 3) {
        const float* aff = (y == 0) ? qa : va;
        float4 a = *(const float4*)(aff + (i & 511));
        f.x *= a.x; f.y *= a.y; f.z *= a.z; f.w *= a.w;
    }
    uint2 u;
    u.x = pack2r(f.x, f.y);
    u.y = pack2r(f.z, f.w);
    *(uint2*)(Wb + (size_t)y * 262144 + i) = u;
}

// ---- QKV projection. Tile 128m x 64n, K-step 64, grid (64, 12).
__global__ __launch_bounds__(256) void qkv_mfma(const float* __restrict__ x,
                                                const ushort_t* __restrict__ Wb,
                                                const float* __restrict__ bqf,
                                                const float* __restrict__ bkf,
                                                const float* __restrict__ bvf,
                                                ushort_t* __restrict__ QT,
                                                ushort_t* __restrict__ KT,
                                                ushort_t* __restrict__ Vb) {
    __shared__ __align__(16) ushort_t Wl[128][72];
    __shared__ __align__(16) ushort_t Bn[64][72];
    __shared__ __align__(16) ushort_t Tl[64][136];
    int t = threadIdx.x;
    int nbase = blockIdx.x << 6;
    int y = blockIdx.y;
    int buf = y >> 2;
    int obase = (y & 3) << 7;
    const ushort_t* Wsrc = Wb + (size_t)buf * 262144;
    const float* bias = (buf == 0) ? bqf : (buf == 1) ? bkf : bvf;

    int w = t >> 6, lane = t & 63, q15 = lane & 15, quad = lane >> 4;
    f32x4 acc[2][4];
    #pragma unroll
    for (int i = 0; i < 2; i++)
        #pragma unroll
        for (int j = 0; j < 4; j++) acc[i][j] = (f32x4){0.f, 0.f, 0.f, 0.f};

    int tok = t & 63, c8 = t >> 6;         // B staging roles
    for (int ck = 0; ck < 512; ck += 64) {
        __syncthreads();
        #pragma unroll
        for (int i = 0; i < 4; i++) {      // A: 1024 uint4 = 128 rows x 64 k
            int idx = 4 * t + i;
            int row = idx >> 3, seg = idx & 7;
            *(uint4*)&Wl[row][seg * 8] =
                *(const uint4*)&Wsrc[(size_t)(obase + row) * 512 + ck + seg * 8];
        }
        {   // B: 64 tok x 64 chans; lane = tok (coalesced), 16 chans each
            float v[16];
            #pragma unroll
            for (int i = 0; i < 16; i++)
                v[i] = x[(size_t)(ck + c8 * 16 + i) * NTOK + nbase + tok];
            uint4 u0, u1;
            u0.x = pack2r(v[0], v[1]);   u0.y = pack2r(v[2], v[3]);
            u0.z = pack2r(v[4], v[5]);   u0.w = pack2r(v[6], v[7]);
            u1.x = pack2r(v[8], v[9]);   u1.y = pack2r(v[10], v[11]);
            u1.z = pack2r(v[12], v[13]); u1.w = pack2r(v[14], v[15]);
            *(uint4*)&Bn[tok][c8 * 16] = u0;
            *(uint4*)&Bn[tok][c8 * 16 + 8] = u1;
        }
        __syncthreads();
        #pragma unroll
        for (int kk = 0; kk < 2; kk++) {
            bf16x8 af0 = ldfrag(&Wl[w * 32 + q15][kk * 32 + quad * 8]);
            bf16x8 af1 = ldfrag(&Wl[w * 32 + 16 + q15][kk * 32 + quad * 8]);
            #pragma unroll
            for (int n8 = 0; n8 < 4; n8++) {
                bf16x8 bfv = ldfrag(&Bn[n8 * 16 + q15][kk * 32 + quad * 8]);
                acc[0][n8] = __builtin_amdgcn_mfma_f32_16x16x32_bf16(af0, bfv, acc[0][n8], 0, 0, 0);
                acc[1][n8] = __builtin_amdgcn_mfma_f32_16x16x32_bf16(af1, bfv, acc[1][n8], 0, 0, 0);
            }
        }
    }

    if (buf == 2) {   // V: f16 [chan][tok]
        #pragma unroll
        for (int mi = 0; mi < 2; mi++)
            #pragma unroll
            for (int r = 0; r < 4; r++) {
                int o = obase + w * 32 + mi * 16 + quad * 4 + r;
                float bo = bias[o];
                #pragma unroll
                for (int n8 = 0; n8 < 4; n8++)
                    Vb[(size_t)o * NTOK + nbase + n8 * 16 + q15] = f2h(acc[mi][n8][r] + bo);
            }
        return;
    }

    // Q/K: transpose via Tl, full 1024-uint4 flush
    ushort_t* dstT = (buf == 0) ? QT : KT;
    float qs = (buf == 0) ? SCALE : 1.0f;
    __syncthreads();
    #pragma unroll
    for (int mi = 0; mi < 2; mi++)
        #pragma unroll
        for (int r = 0; r < 4; r++) {
            int mloc = w * 32 + mi * 16 + quad * 4 + r;
            float bo = bias[obase + mloc];
            #pragma unroll
            for (int n8 = 0; n8 < 4; n8++)
                Tl[n8 * 16 + q15][mloc] = f2b((acc[mi][n8][r] + bo) * qs);
        }
    __syncthreads();
    #pragma unroll
    for (int i = 0; i < 4; i++) {
        int idx = 4 * t + i;                // 1024 uint4: 64 rows x 16 segs
        int row = idx >> 4, ch = idx & 15;
        uint4 u = *(const uint4*)&Tl[row][ch * 8];
        *(uint4*)&dstT[(size_t)(nbase + row) * 512 + obase + ch * 8] = u;
    }
}

// ---- Attention v13: register-direct P (key permutation, proven) + async
// DMA double-buffer via global_load_lds. No reg staging (v12's spill bug),
// no ds_write staging (v11's write-side bank conflicts). One barrier per
// 256-key tile; its vmcnt(0) drain lands AFTER the 4 h2 sub-passes, so the
// prefetch hides under compute. LDS linear (DMA requires it); read-side
// conflicts fixed by pre-swizzling the GLOBAL source granule (m173 pattern):
//   K: slot(row,g) holds granule g ^ ((row>>1)&3)  -> reads 2-way (free)
//   V: slot(d,g)   holds granule g ^ (d&7)         -> reads 2-way (free)
__global__ __launch_bounds__(512, 4) void attn_v13(ushort_t* __restrict__ QT,
                                                   const ushort_t* __restrict__ KT,
                                                   const ushort_t* __restrict__ V) {
    __shared__ __align__(16) ushort_t KtF[2][8192];  // [buf][256 keys x 4 gran x 8] swz
    __shared__ __align__(16) ushort_t VtF[2][8192];  // [buf][32 d x 32 gran x 8] swz
    int h = blockIdx.y;
    int t = threadIdx.x;
    int w = t >> 6, lane = t & 63, q15 = lane & 15, quad = lane >> 4;
    int qbase = (blockIdx.x << 7) + w * 16;          // wave-private 16 queries
    int hc = h * 32;
    const ushort_t* Vh = V + (size_t)hc * NTOK;

    bf16x8 qf = ldfrag(&QT[(size_t)(qbase + q15) * 512 + hc + quad * 8]);

    const uint4 onesu = {0x3C003C00u, 0x3C003C00u, 0x3C003C00u, 0x3C003C00u};
    const f16x8 ones = __builtin_bit_cast(f16x8, onesu);

    f32x4 o[2] = {{0.f, 0.f, 0.f, 0.f}, {0.f, 0.f, 0.f, 0.f}};
    f32x4 lacc = {0.f, 0.f, 0.f, 0.f};

    auto issue = [&](int j0, int b) {
        #pragma unroll
        for (int i = 0; i < 2; i++) {      // K: 1024 slots, 2 wave-instructions x 8 waves
            int sbase = (w << 6) + (i << 9);
            int idx = sbase + lane;
            int krow = idx >> 2;
            int gd = (idx & 3) ^ ((krow >> 1) & 3);
            int rp = krow & 63;            // key permutation (register-direct P)
            int srcr = (krow & 192) | (rp & 0x23) | ((rp & 0x0C) << 1) | ((rp & 0x10) >> 2);
            ldg2lds16(&KT[(size_t)(j0 + srcr) * 512 + hc + gd * 8],
                      &KtF[b][sbase * 8]);
        }
        #pragma unroll
        for (int i = 0; i < 2; i++) {      // V: 1024 slots
            int sbase = (w << 6) + (i << 9);
            int idx = sbase + lane;
            int d = idx >> 5;
            int gd = (idx & 31) ^ (d & 7);
            ldg2lds16(&Vh[(size_t)d * NTOK + j0 + gd * 8],
                      &VtF[b][sbase * 8]);
        }
    };

    issue(0, 0);
    int ksp8 = (quad ^ ((q15 >> 1) & 3)) * 8;   // K read granule offset (swz, invariant)
    int vq = q15 & 7;                           // V read swz key

    for (int tt = 0; tt < 16; tt++) {
        int cur = tt & 1;
        __syncthreads();                   // drains DMA for buf[cur]; all waves done with buf[cur^1]
        if (tt < 15) issue((tt + 1) << 8, cur ^ 1);
        const ushort_t* KtC = KtF[cur];
        const ushort_t* VtC = VtF[cur];

        #pragma unroll
        for (int h2 = 0; h2 < 4; h2++) {   // four 64-key sub-passes
            f32x4 st[4];
            __builtin_amdgcn_s_setprio(1);
            #pragma unroll
            for (int kt = 0; kt < 4; kt++) {
                bf16x8 kf = ldfrag(&KtC[(h2 * 64 + kt * 16 + q15) * 32 + ksp8]);
                f32x4 z = {0.f, 0.f, 0.f, 0.f};
                st[kt] = __builtin_amdgcn_mfma_f32_16x16x32_bf16(kf, qf, z, 0, 0, 0);
            }
            __builtin_amdgcn_s_setprio(0);

            #pragma unroll
            for (int kt = 0; kt < 4; kt++)
                #pragma unroll
                for (int r = 0; r < 4; r++)
                    st[kt][r] = __expf(st[kt][r]);

            int g0 = ((h2 * 8 + quad) ^ vq) * 8;
            int g1 = g0 ^ 32;              // (x^4)*8 == (x*8)^32 for quad<4
            f16x8 v00 = ldfragh(&VtC[q15 * 256 + g0]);
            f16x8 v01 = ldfragh(&VtC[(16 + q15) * 256 + g0]);
            f16x8 v10 = ldfragh(&VtC[q15 * 256 + g1]);
            f16x8 v11 = ldfragh(&VtC[(16 + q15) * 256 + g1]);

            uint4 p0u, p1u;
            p0u.x = packh2(st[0][0], st[0][1]);
            p0u.y = packh2(st[0][2], st[0][3]);
            p0u.z = packh2(st[1][0], st[1][1]);
            p0u.w = packh2(st[1][2], st[1][3]);
            p1u.x = packh2(st[2][0], st[2][1]);
            p1u.y = packh2(st[2][2], st[2][3]);
            p1u.z = packh2(st[3][0], st[3][1]);
            p1u.w = packh2(st[3][2], st[3][3]);
            f16x8 pf0 = __builtin_bit_cast(f16x8, p0u);
            f16x8 pf1 = __builtin_bit_cast(f16x8, p1u);
            __builtin_amdgcn_s_setprio(1);
            o[0] = __builtin_amdgcn_mfma_f32_16x16x32_f16(pf0, v00, o[0], 0, 0, 0);
            o[1] = __builtin_amdgcn_mfma_f32_16x16x32_f16(pf0, v01, o[1], 0, 0, 0);
            lacc = __builtin_amdgcn_mfma_f32_16x16x32_f16(pf0, ones, lacc, 0, 0, 0);
            o[0] = __builtin_amdgcn_mfma_f32_16x16x32_f16(pf1, v10, o[0], 0, 0, 0);
            o[1] = __builtin_amdgcn_mfma_f32_16x16x32_f16(pf1, v11, o[1], 0, 0, 0);
            lacc = __builtin_amdgcn_mfma_f32_16x16x32_f16(pf1, ones, lacc, 0, 0, 0);
            __builtin_amdgcn_s_setprio(0);
        }
    }

    #pragma unroll
    for (int r = 0; r < 4; r++) {
        float li = 1.f / lacc[r];
        int q = quad * 4 + r;
        QT[(size_t)(qbase + q) * 512 + hc + q15]      = f2b(o[0][r] * li);
        QT[(size_t)(qbase + q) * 512 + hc + 16 + q15] = f2b(o[1][r] * li);
    }
}

// ---- Output projection: tile 64m x 64n, grid (64, 8). A = Wb[3] copy-staged.
__global__ __launch_bounds__(256) void oproj_mfma(const ushort_t* __restrict__ OT,
                                                  const ushort_t* __restrict__ Wob,
                                                  const float* __restrict__ bo,
                                                  const float* __restrict__ x,
                                                  float* __restrict__ out) {
    __shared__ __align__(16) ushort_t Wl[64][40];
    __shared__ __align__(16) ushort_t Bn[64][40];
    int t = threadIdx.x;
    int nbase = blockIdx.x << 6;
    int obase = blockIdx.y << 6;
    int w = t >> 6, lane = t & 63, q15 = lane & 15, quad = lane >> 4;

    f32x4 acc[4];
    #pragma unroll
    for (int i = 0; i < 4; i++) acc[i] = (f32x4){0.f, 0.f, 0.f, 0.f};

    int arow = t >> 2, aseg = t & 3;
    for (int ck = 0; ck < 512; ck += 32) {
        __syncthreads();
        *(uint4*)&Wl[arow][aseg * 8] =
            *(const uint4*)&Wob[(size_t)(obase + arow) * 512 + ck + aseg * 8];
        *(uint4*)&Bn[arow][aseg * 8] =
            *(const uint4*)&OT[(size_t)(nbase + arow) * 512 + ck + aseg * 8];
        __syncthreads();
        bf16x8 af = ldfrag(&Wl[w * 16 + q15][quad * 8]);
        #pragma unroll
        for (int n8 = 0; n8 < 4; n8++) {
            bf16x8 bfv = ldfrag(&Bn[n8 * 16 + q15][quad * 8]);
            acc[n8] = __builtin_amdgcn_mfma_f32_16x16x32_bf16(af, bfv, acc[n8], 0, 0, 0);
        }
    }

    #pragma unroll
    for (int r = 0; r < 4; r++) {
        int o = obase + w * 16 + quad * 4 + r;
        float b = bo[o];
        #pragma unroll
        for (int n8 = 0; n8 < 4; n8++) {
            size_t idx = (size_t)o * NTOK + nbase + n8 * 16 + q15;
            out[idx] = (acc[n8][r] + b + x[idx]) * RSQRT2;
        }
    }
}

extern "C" void kernel_launch(void* const* d_in, const int* in_sizes, int n_in,
                              void* d_out, int out_size, void* d_ws, size_t ws_size,
                              hipStream_t stream) {
    const float* x   = (const float*)d_in[0];
    const float* gnw = (const float*)d_in[1];
    const float* gnb = (const float*)d_in[2];
    const float* wq  = (const float*)d_in[3];
    const float* bq  = (const float*)d_in[4];
    const float* wk  = (const float*)d_in[5];
    const float* bk  = (const float*)d_in[6];
    const float* wv  = (const float*)d_in[7];
    const float* bv  = (const float*)d_in[8];
    const float* wo  = (const float*)d_in[9];
    const float* bo  = (const float*)d_in[10];
    float* out = (float*)d_out;

    if (ws_size < WS_NEEDED) {
        diag_kernel<<<1, 64, 0, stream>>>(out, (float)(ws_size >> 16));
        return;
    }

    char* wsb = (char*)d_ws;
    float* S   = (float*)(wsb + 0);
    float* SS  = (float*)(wsb + 2048);
    float* qa  = (float*)(wsb + 4096);
    float* qd  = (float*)(wsb + 6144);
    float* va  = (float*)(wsb + 8192);
    float* vd  = (float*)(wsb + 10240);
    float* bqf = (float*)(wsb + 12288);
    float* bkf = (float*)(wsb + 14336);
    float* bvf = (float*)(wsb + 16384);
    ushort_t* Wb = (ushort_t*)(wsb + WB_OFF);    // 2 MB bf16 (wq'|wk'|wv'|wo)
    ushort_t* QT = (ushort_t*)(wsb + QT_OFF);    // 4 MB bf16 [4096][512] (becomes O)
    ushort_t* KT = (ushort_t*)d_out;                        // 4 MB bf16 [4096][512]
    ushort_t* Vb = (ushort_t*)d_out + (size_t)CHAN * NTOK;  // 4 MB f16 [512][4096]

    gn_sums<<<512, 256, 0, stream>>>(x, S, SS);
    gn_coef<<<1, 512, 0, stream>>>(S, SS, gnw, gnb, qa, qd, va, vd);
    bias_fold<<<384, 256, 0, stream>>>(wq, wk, wv, bq, bk, bv, qd, vd, bqf, bkf, bvf);
    wprep<<<dim3(256, 4), 256, 0, stream>>>(wq, wk, wv, wo, qa, va, Wb);

    qkv_mfma<<<dim3(64, 12), 256, 0, stream>>>(x, Wb, bqf, bkf, bvf, QT, KT, Vb);

    attn_v13<<<dim3(32, 16), 512, 0, stream>>>(QT, KT, Vb);

    oproj_mfma<<<dim3(64, 8), 256, 0, stream>>>(QT, Wb + (size_t)3 * 262144, bo, x, out);
}

// Round 6
// 163.102 us; speedup vs baseline: 1.2008x; 1.0209x over previous
//
#include <hip/hip_runtime.h>

#define NTOK 4096
#define CHAN 512
#define GSIZE 65536
#define RSQRT2 0.7071067811865476f
#define SCALEX 0.2550348837f        // (1/sqrt(32)) * log2(e); attn uses raw 2^x
#define WB_OFF 32768
#define QT_OFF (WB_OFF + 2097152)
#define WS_NEEDED ((size_t)(QT_OFF + 4194304))

typedef unsigned short ushort_t;
typedef __attribute__((ext_vector_type(8))) short bf16x8;
typedef __attribute__((ext_vector_type(8))) _Float16 f16x8;
typedef __attribute__((ext_vector_type(4))) float f32x4;

__device__ __forceinline__ ushort_t f2b(float f) {
    unsigned u = __float_as_uint(f);
    unsigned r = (u + 0x7FFFu + ((u >> 16) & 1u)) >> 16;
    return (ushort_t)r;
}
__device__ __forceinline__ unsigned pack2r(float a, float b) {
    unsigned ua = __float_as_uint(a), ub = __float_as_uint(b);
    return ((ua + 0x8000u) >> 16) | ((ub + 0x8000u) & 0xFFFF0000u);
}
__device__ __forceinline__ unsigned packh2(float a, float b) {
    return __builtin_bit_cast(unsigned, __builtin_amdgcn_cvt_pkrtz(a, b));
}
__device__ __forceinline__ ushort_t f2h(float f) {
    return (ushort_t)(packh2(f, f) & 0xFFFFu);
}
__device__ __forceinline__ bf16x8 ldfrag(const ushort_t* p) {
    return __builtin_bit_cast(bf16x8, *(const uint4*)p);
}
__device__ __forceinline__ f16x8 ldfragh(const ushort_t* p) {
    return __builtin_bit_cast(f16x8, *(const uint4*)p);
}
// raw v_exp_f32 (2^x) with compiler-managed hazards; fallback stays correct
__device__ __forceinline__ float exp2_raw(float x) {
#if __has_builtin(__builtin_amdgcn_exp2f)
    return __builtin_amdgcn_exp2f(x);
#else
    return __expf(x * 0.6931471805599453f);
#endif
}
// async global->LDS DMA, 16B per lane; LDS dest = wave-uniform base + lane*16
__device__ __forceinline__ void ldg2lds16(const void* g, void* l) {
    __builtin_amdgcn_global_load_lds(
        (const __attribute__((address_space(1))) void*)g,
        (__attribute__((address_space(3))) void*)l, 16, 0, 0);
}

__global__ void diag_kernel(float* out, float v) {
    if (threadIdx.x == 0 && blockIdx.x == 0) out[0] = v;
}

// ---- GN pass A: per-channel sums. One block per channel (512 blocks).
__global__ __launch_bounds__(256) void gn_sums(const float* __restrict__ x,
                                               float* __restrict__ S,
                                               float* __restrict__ SS) {
    int c = blockIdx.x, t = threadIdx.x;
    const float4* p = (const float4*)(x + (size_t)c * 4096);
    float s = 0.f, ss = 0.f;
    #pragma unroll
    for (int i = 0; i < 4; i++) {
        float4 f = p[i * 256 + t];
        s += f.x + f.y + f.z + f.w;
        ss += f.x * f.x + f.y * f.y + f.z * f.z + f.w * f.w;
    }
    #pragma unroll
    for (int off = 32; off > 0; off >>= 1) {
        s += __shfl_xor(s, off);
        ss += __shfl_xor(ss, off);
    }
    __shared__ float as[4], bs[4];
    int w = t >> 6;
    if ((t & 63) == 0) { as[w] = s; bs[w] = ss; }
    __syncthreads();
    if (t == 0) {
        S[c] = as[0] + as[1] + as[2] + as[3];
        SS[c] = bs[0] + bs[1] + bs[2] + bs[3];
    }
}

// ---- GN pass B: coefficients. 1 block x 512 threads (thread = channel).
__global__ __launch_bounds__(512) void gn_coef(const float* __restrict__ S,
                                               const float* __restrict__ SS,
                                               const float* __restrict__ gnw,
                                               const float* __restrict__ gnb,
                                               float* __restrict__ qa,
                                               float* __restrict__ qd,
                                               float* __restrict__ va,
                                               float* __restrict__ vd) {
    int c = threadIdx.x;
    float Sc = S[c], SSc = SS[c];
    float gs = Sc, gss = SSc;
    #pragma unroll
    for (int off = 1; off < 16; off <<= 1) {
        gs += __shfl_xor(gs, off);
        gss += __shfl_xor(gss, off);
    }
    float mu = gs * (1.f / GSIZE);
    float var = gss * (1.f / GSIZE) - mu * mu;
    float r1 = rsqrtf(var + 1e-6f);
    float wc = gnw[c], bc = gnb[c];
    float a1 = r1 * wc;
    float d1 = bc - mu * a1;
    qa[c] = a1; qd[c] = d1;
    float S2 = a1 * Sc + 4096.f * d1;
    float SS2 = a1 * a1 * SSc + 2.f * a1 * d1 * Sc + 4096.f * d1 * d1;
    float gs2 = S2, gss2 = SS2;
    #pragma unroll
    for (int off = 1; off < 16; off <<= 1) {
        gs2 += __shfl_xor(gs2, off);
        gss2 += __shfl_xor(gss2, off);
    }
    float mu2 = gs2 * (1.f / GSIZE);
    float var2 = gss2 * (1.f / GSIZE) - mu2 * mu2;
    float r2 = rsqrtf(var2 + 1e-6f);
    float a2 = r2 * wc;
    va[c] = a1 * a2;
    vd[c] = a2 * (d1 - mu2) + bc;
}

// ---- Fused prep: blocks 0..383 = bias_fold; blocks 384..1407 = wprep.
__global__ __launch_bounds__(256) void prep_all(const float* __restrict__ wq,
                                                const float* __restrict__ wk,
                                                const float* __restrict__ wv,
                                                const float* __restrict__ wo,
                                                const float* __restrict__ bq,
                                                const float* __restrict__ bk,
                                                const float* __restrict__ bv,
                                                const float* __restrict__ qa,
                                                const float* __restrict__ qd,
                                                const float* __restrict__ va,
                                                const float* __restrict__ vd,
                                                float* __restrict__ bqf,
                                                float* __restrict__ bkf,
                                                float* __restrict__ bvf,
                                                ushort_t* __restrict__ Wb) {
    int bx = blockIdx.x;
    if (bx < 384) {   // bias fold: b'[o] = b[o] + sum_c W[o][c]*d[c]
        int row = bx * 4 + (threadIdx.x >> 6);   // 0..1535
        int lane = threadIdx.x & 63;
        int m = row >> 9;
        int o = row & 511;
        const float* W = (m == 0) ? wq : (m == 1) ? wk : wv;
        const float* b = (m == 0) ? bq : (m == 1) ? bk : bv;
        const float* d = (m == 0) ? qd : vd;
        float* outp    = (m == 0) ? bqf : (m == 1) ? bkf : bvf;
        const float4* wr = (const float4*)(W + (size_t)o * 512) + lane * 2;
        const float4* dr = (const float4*)d + lane * 2;
        float4 a0 = wr[0], a1 = wr[1], d0 = dr[0], d1 = dr[1];
        float acc = a0.x * d0.x + a0.y * d0.y + a0.z * d0.z + a0.w * d0.w
                  + a1.x * d1.x + a1.y * d1.y + a1.z * d1.z + a1.w * d1.w;
        #pragma unroll
        for (int off = 32; off > 0; off >>= 1) acc += __shfl_xor(acc, off);
        if (lane == 0) outp[o] = b[o] + acc;
    } else {          // weight prep: fp32 -> bf16, GN affine folded
        int idx = bx - 384;                      // 0..1023
        int y = idx >> 8;
        const float* src = (y == 0) ? wq : (y == 1) ? wk : (y == 2) ? wv : wo;
        int i = ((idx & 255) * 256 + threadIdx.x) * 4;
        float4 f = *(const float4*)(src + i);
        if (y < 3) {
            const float* aff = (y == 0) ? qa : va;
            float4 a = *(const float4*)(aff + (i & 511));
            f.x *= a.x; f.y *= a.y; f.z *= a.z; f.w *= a.w;
        }
        uint2 u;
        u.x = pack2r(f.x, f.y);
        u.y = pack2r(f.z, f.w);
        *(uint2*)(Wb + (size_t)y * 262144 + i) = u;
    }
}

// ---- QKV projection. Tile 128m x 64n, K-step 64, grid (64, 12).
__global__ __launch_bounds__(256) void qkv_mfma(const float* __restrict__ x,
                                                const ushort_t* __restrict__ Wb,
                                                const float* __restrict__ bqf,
                                                const float* __restrict__ bkf,
                                                const float* __restrict__ bvf,
                                                ushort_t* __restrict__ QT,
                                                ushort_t* __restrict__ KT,
                                                ushort_t* __restrict__ Vb) {
    __shared__ __align__(16) ushort_t Wl[128][72];
    __shared__ __align__(16) ushort_t Bn[64][72];
    __shared__ __align__(16) ushort_t Tl[64][136];
    int t = threadIdx.x;
    int nbase = blockIdx.x << 6;
    int y = blockIdx.y;
    int buf = y >> 2;
    int obase = (y & 3) << 7;
    const ushort_t* Wsrc = Wb + (size_t)buf * 262144;
    const float* bias = (buf == 0) ? bqf : (buf == 1) ? bkf : bvf;

    int w = t >> 6, lane = t & 63, q15 = lane & 15, quad = lane >> 4;
    f32x4 acc[2][4];
    #pragma unroll
    for (int i = 0; i < 2; i++)
        #pragma unroll
        for (int j = 0; j < 4; j++) acc[i][j] = (f32x4){0.f, 0.f, 0.f, 0.f};

    int tok = t & 63, c8 = t >> 6;         // B staging roles
    for (int ck = 0; ck < 512; ck += 64) {
        __syncthreads();
        #pragma unroll
        for (int i = 0; i < 4; i++) {      // A: 1024 uint4 = 128 rows x 64 k
            int idx = 4 * t + i;
            int row = idx >> 3, seg = idx & 7;
            *(uint4*)&Wl[row][seg * 8] =
                *(const uint4*)&Wsrc[(size_t)(obase + row) * 512 + ck + seg * 8];
        }
        {   // B: 64 tok x 64 chans; lane = tok (coalesced), 16 chans each
            float v[16];
            #pragma unroll
            for (int i = 0; i < 16; i++)
                v[i] = x[(size_t)(ck + c8 * 16 + i) * NTOK + nbase + tok];
            uint4 u0, u1;
            u0.x = pack2r(v[0], v[1]);   u0.y = pack2r(v[2], v[3]);
            u0.z = pack2r(v[4], v[5]);   u0.w = pack2r(v[6], v[7]);
            u1.x = pack2r(v[8], v[9]);   u1.y = pack2r(v[10], v[11]);
            u1.z = pack2r(v[12], v[13]); u1.w = pack2r(v[14], v[15]);
            *(uint4*)&Bn[tok][c8 * 16] = u0;
            *(uint4*)&Bn[tok][c8 * 16 + 8] = u1;
        }
        __syncthreads();
        #pragma unroll
        for (int kk = 0; kk < 2; kk++) {
            bf16x8 af0 = ldfrag(&Wl[w * 32 + q15][kk * 32 + quad * 8]);
            bf16x8 af1 = ldfrag(&Wl[w * 32 + 16 + q15][kk * 32 + quad * 8]);
            #pragma unroll
            for (int n8 = 0; n8 < 4; n8++) {
                bf16x8 bfv = ldfrag(&Bn[n8 * 16 + q15][kk * 32 + quad * 8]);
                acc[0][n8] = __builtin_amdgcn_mfma_f32_16x16x32_bf16(af0, bfv, acc[0][n8], 0, 0, 0);
                acc[1][n8] = __builtin_amdgcn_mfma_f32_16x16x32_bf16(af1, bfv, acc[1][n8], 0, 0, 0);
            }
        }
    }

    if (buf == 2) {   // V: f16 [chan][tok]
        #pragma unroll
        for (int mi = 0; mi < 2; mi++)
            #pragma unroll
            for (int r = 0; r < 4; r++) {
                int o = obase + w * 32 + mi * 16 + quad * 4 + r;
                float bo = bias[o];
                #pragma unroll
                for (int n8 = 0; n8 < 4; n8++)
                    Vb[(size_t)o * NTOK + nbase + n8 * 16 + q15] = f2h(acc[mi][n8][r] + bo);
            }
        return;
    }

    // Q/K: transpose via Tl, full 1024-uint4 flush. Q carries SCALEX (2^x attn).
    ushort_t* dstT = (buf == 0) ? QT : KT;
    float qs = (buf == 0) ? SCALEX : 1.0f;
    __syncthreads();
    #pragma unroll
    for (int mi = 0; mi < 2; mi++)
        #pragma unroll
        for (int r = 0; r < 4; r++) {
            int mloc = w * 32 + mi * 16 + quad * 4 + r;
            float bo = bias[obase + mloc];
            #pragma unroll
            for (int n8 = 0; n8 < 4; n8++)
                Tl[n8 * 16 + q15][mloc] = f2b((acc[mi][n8][r] + bo) * qs);
        }
    __syncthreads();
    #pragma unroll
    for (int i = 0; i < 4; i++) {
        int idx = 4 * t + i;                // 1024 uint4: 64 rows x 16 segs
        int row = idx >> 4, ch = idx & 15;
        uint4 u = *(const uint4*)&Tl[row][ch * 8];
        *(uint4*)&dstT[(size_t)(nbase + row) * 512 + obase + ch * 8] = u;
    }
}

// ---- Attention v14: v13 (register-direct P, DMA double-buffer, source
// swizzle) + log2e folded into Q at prep time so softmax uses raw v_exp_f32
// (2^x) — drops 16 v_mul per h2 (~10% of VALU busy).
__global__ __launch_bounds__(512, 4) void attn_v14(ushort_t* __restrict__ QT,
                                                   const ushort_t* __restrict__ KT,
                                                   const ushort_t* __restrict__ V) {
    __shared__ __align__(16) ushort_t KtF[2][8192];  // [buf][256 keys x 4 gran x 8] swz
    __shared__ __align__(16) ushort_t VtF[2][8192];  // [buf][32 d x 32 gran x 8] swz
    int h = blockIdx.y;
    int t = threadIdx.x;
    int w = t >> 6, lane = t & 63, q15 = lane & 15, quad = lane >> 4;
    int qbase = (blockIdx.x << 7) + w * 16;          // wave-private 16 queries
    int hc = h * 32;
    const ushort_t* Vh = V + (size_t)hc * NTOK;

    bf16x8 qf = ldfrag(&QT[(size_t)(qbase + q15) * 512 + hc + quad * 8]);

    const uint4 onesu = {0x3C003C00u, 0x3C003C00u, 0x3C003C00u, 0x3C003C00u};
    const f16x8 ones = __builtin_bit_cast(f16x8, onesu);

    f32x4 o[2] = {{0.f, 0.f, 0.f, 0.f}, {0.f, 0.f, 0.f, 0.f}};
    f32x4 lacc = {0.f, 0.f, 0.f, 0.f};

    auto issue = [&](int j0, int b) {
        #pragma unroll
        for (int i = 0; i < 2; i++) {      // K: 1024 slots
            int sbase = (w << 6) + (i << 9);
            int idx = sbase + lane;
            int krow = idx >> 2;
            int gd = (idx & 3) ^ ((krow >> 1) & 3);
            int rp = krow & 63;            // key permutation (register-direct P)
            int srcr = (krow & 192) | (rp & 0x23) | ((rp & 0x0C) << 1) | ((rp & 0x10) >> 2);
            ldg2lds16(&KT[(size_t)(j0 + srcr) * 512 + hc + gd * 8],
                      &KtF[b][sbase * 8]);
        }
        #pragma unroll
        for (int i = 0; i < 2; i++) {      // V: 1024 slots
            int sbase = (w << 6) + (i << 9);
            int idx = sbase + lane;
            int d = idx >> 5;
            int gd = (idx & 31) ^ (d & 7);
            ldg2lds16(&Vh[(size_t)d * NTOK + j0 + gd * 8],
                      &VtF[b][sbase * 8]);
        }
    };

    issue(0, 0);
    int ksp8 = (quad ^ ((q15 >> 1) & 3)) * 8;   // K read granule offset (swz)
    int vq = q15 & 7;                           // V read swz key

    for (int tt = 0; tt < 16; tt++) {
        int cur = tt & 1;
        __syncthreads();                   // drains DMA for buf[cur]
        if (tt < 15) issue((tt + 1) << 8, cur ^ 1);
        const ushort_t* KtC = KtF[cur];
        const ushort_t* VtC = VtF[cur];

        #pragma unroll
        for (int h2 = 0; h2 < 4; h2++) {   // four 64-key sub-passes
            f32x4 st[4];
            __builtin_amdgcn_s_setprio(1);
            #pragma unroll
            for (int kt = 0; kt < 4; kt++) {
                bf16x8 kf = ldfrag(&KtC[(h2 * 64 + kt * 16 + q15) * 32 + ksp8]);
                f32x4 z = {0.f, 0.f, 0.f, 0.f};
                st[kt] = __builtin_amdgcn_mfma_f32_16x16x32_bf16(kf, qf, z, 0, 0, 0);
            }
            __builtin_amdgcn_s_setprio(0);

            #pragma unroll
            for (int kt = 0; kt < 4; kt++)
                #pragma unroll
                for (int r = 0; r < 4; r++)
                    st[kt][r] = exp2_raw(st[kt][r]);

            int g0 = ((h2 * 8 + quad) ^ vq) * 8;
            int g1 = g0 ^ 32;              // (x^4)*8 == (x*8)^32 for quad<4
            f16x8 v00 = ldfragh(&VtC[q15 * 256 + g0]);
            f16x8 v01 = ldfragh(&VtC[(16 + q15) * 256 + g0]);
            f16x8 v10 = ldfragh(&VtC[q15 * 256 + g1]);
            f16x8 v11 = ldfragh(&VtC[(16 + q15) * 256 + g1]);

            uint4 p0u, p1u;
            p0u.x = packh2(st[0][0], st[0][1]);
            p0u.y = packh2(st[0][2], st[0][3]);
            p0u.z = packh2(st[1][0], st[1][1]);
            p0u.w = packh2(st[1][2], st[1][3]);
            p1u.x = packh2(st[2][0], st[2][1]);
            p1u.y = packh2(st[2][2], st[2][3]);
            p1u.z = packh2(st[3][0], st[3][1]);
            p1u.w = packh2(st[3][2], st[3][3]);
            f16x8 pf0 = __builtin_bit_cast(f16x8, p0u);
            f16x8 pf1 = __builtin_bit_cast(f16x8, p1u);
            __builtin_amdgcn_s_setprio(1);
            o[0] = __builtin_amdgcn_mfma_f32_16x16x32_f16(pf0, v00, o[0], 0, 0, 0);
            o[1] = __builtin_amdgcn_mfma_f32_16x16x32_f16(pf0, v01, o[1], 0, 0, 0);
            lacc = __builtin_amdgcn_mfma_f32_16x16x32_f16(pf0, ones, lacc, 0, 0, 0);
            o[0] = __builtin_amdgcn_mfma_f32_16x16x32_f16(pf1, v10, o[0], 0, 0, 0);
            o[1] = __builtin_amdgcn_mfma_f32_16x16x32_f16(pf1, v11, o[1], 0, 0, 0);
            lacc = __builtin_amdgcn_mfma_f32_16x16x32_f16(pf1, ones, lacc, 0, 0, 0);
            __builtin_amdgcn_s_setprio(0);
        }
    }

    #pragma unroll
    for (int r = 0; r < 4; r++) {
        float li = 1.f / lacc[r];
        int q = quad * 4 + r;
        QT[(size_t)(qbase + q) * 512 + hc + q15]      = f2b(o[0][r] * li);
        QT[(size_t)(qbase + q) * 512 + hc + 16 + q15] = f2b(o[1][r] * li);
    }
}

// ---- Output projection: tile 64m x 64n, K-step 64 (8 staged steps, halved
// barrier count vs K-step 32), grid (64, 8).
__global__ __launch_bounds__(256) void oproj_mfma(const ushort_t* __restrict__ OT,
                                                  const ushort_t* __restrict__ Wob,
                                                  const float* __restrict__ bo,
                                                  const float* __restrict__ x,
                                                  float* __restrict__ out) {
    __shared__ __align__(16) ushort_t Wl[64][72];
    __shared__ __align__(16) ushort_t Bn[64][72];
    int t = threadIdx.x;
    int nbase = blockIdx.x << 6;
    int obase = blockIdx.y << 6;
    int w = t >> 6, lane = t & 63, q15 = lane & 15, quad = lane >> 4;

    f32x4 acc[4];
    #pragma unroll
    for (int i = 0; i < 4; i++) acc[i] = (f32x4){0.f, 0.f, 0.f, 0.f};

    for (int ck = 0; ck < 512; ck += 64) {
        __syncthreads();
        #pragma unroll
        for (int i = 0; i < 2; i++) {      // 512 uint4 per tile, 2 per thread
            int idx = t * 2 + i;
            int row = idx >> 3, seg = idx & 7;
            *(uint4*)&Wl[row][seg * 8] =
                *(const uint4*)&Wob[(size_t)(obase + row) * 512 + ck + seg * 8];
            *(uint4*)&Bn[row][seg * 8] =
                *(const uint4*)&OT[(size_t)(nbase + row) * 512 + ck + seg * 8];
        }
        __syncthreads();
        #pragma unroll
        for (int kk = 0; kk < 2; kk++) {
            bf16x8 af = ldfrag(&Wl[w * 16 + q15][kk * 32 + quad * 8]);
            #pragma unroll
            for (int n8 = 0; n8 < 4; n8++) {
                bf16x8 bfv = ldfrag(&Bn[n8 * 16 + q15][kk * 32 + quad * 8]);
                acc[n8] = __builtin_amdgcn_mfma_f32_16x16x32_bf16(af, bfv, acc[n8], 0, 0, 0);
            }
        }
    }

    #pragma unroll
    for (int r = 0; r < 4; r++) {
        int o = obase + w * 16 + quad * 4 + r;
        float b = bo[o];
        #pragma unroll
        for (int n8 = 0; n8 < 4; n8++) {
            size_t idx = (size_t)o * NTOK + nbase + n8 * 16 + q15;
            out[idx] = (acc[n8][r] + b + x[idx]) * RSQRT2;
        }
    }
}

extern "C" void kernel_launch(void* const* d_in, const int* in_sizes, int n_in,
                              void* d_out, int out_size, void* d_ws, size_t ws_size,
                              hipStream_t stream) {
    const float* x   = (const float*)d_in[0];
    const float* gnw = (const float*)d_in[1];
    const float* gnb = (const float*)d_in[2];
    const float* wq  = (const float*)d_in[3];
    const float* bq  = (const float*)d_in[4];
    const float* wk  = (const float*)d_in[5];
    const float* bk  = (const float*)d_in[6];
    const float* wv  = (const float*)d_in[7];
    const float* bv  = (const float*)d_in[8];
    const float* wo  = (const float*)d_in[9];
    const float* bo  = (const float*)d_in[10];
    float* out = (float*)d_out;

    if (ws_size < WS_NEEDED) {
        diag_kernel<<<1, 64, 0, stream>>>(out, (float)(ws_size >> 16));
        return;
    }

    char* wsb = (char*)d_ws;
    float* S   = (float*)(wsb + 0);
    float* SS  = (float*)(wsb + 2048);
    float* qa  = (float*)(wsb + 4096);
    float* qd  = (float*)(wsb + 6144);
    float* va  = (float*)(wsb + 8192);
    float* vd  = (float*)(wsb + 10240);
    float* bqf = (float*)(wsb + 12288);
    float* bkf = (float*)(wsb + 14336);
    float* bvf = (float*)(wsb + 16384);
    ushort_t* Wb = (ushort_t*)(wsb + WB_OFF);    // 2 MB bf16 (wq'|wk'|wv'|wo)
    ushort_t* QT = (ushort_t*)(wsb + QT_OFF);    // 4 MB bf16 [4096][512] (becomes O)
    ushort_t* KT = (ushort_t*)d_out;                        // 4 MB bf16 [4096][512]
    ushort_t* Vb = (ushort_t*)d_out + (size_t)CHAN * NTOK;  // 4 MB f16 [512][4096]

    gn_sums<<<512, 256, 0, stream>>>(x, S, SS);
    gn_coef<<<1, 512, 0, stream>>>(S, SS, gnw, gnb, qa, qd, va, vd);
    prep_all<<<1408, 256, 0, stream>>>(wq, wk, wv, wo, bq, bk, bv,
                                       qa, qd, va, vd, bqf, bkf, bvf, Wb);

    qkv_mfma<<<dim3(64, 12), 256, 0, stream>>>(x, Wb, bqf, bkf, bvf, QT, KT, Vb);

    attn_v14<<<dim3(32, 16), 512, 0, stream>>>(QT, KT, Vb);

    oproj_mfma<<<dim3(64, 8), 256, 0, stream>>>(QT, Wb + (size_t)3 * 262144, bo, x, out);
}

// Round 7
// 161.695 us; speedup vs baseline: 1.2113x; 1.0087x over previous
//
#include <hip/hip_runtime.h>

#define NTOK 4096
#define CHAN 512
#define GSIZE 65536
#define RSQRT2 0.7071067811865476f
#define SCALEX 0.2550348837f        // (1/sqrt(32)) * log2(e); attn uses raw 2^x
#define WB_OFF 32768
#define QT_OFF (WB_OFF + 2097152)
#define WS_NEEDED ((size_t)(QT_OFF + 4194304))

typedef unsigned short ushort_t;
typedef __attribute__((ext_vector_type(8))) short bf16x8;
typedef __attribute__((ext_vector_type(8))) _Float16 f16x8;
typedef __attribute__((ext_vector_type(4))) float f32x4;

__device__ __forceinline__ ushort_t f2b(float f) {
    unsigned u = __float_as_uint(f);
    unsigned r = (u + 0x7FFFu + ((u >> 16) & 1u)) >> 16;
    return (ushort_t)r;
}
__device__ __forceinline__ unsigned pack2r(float a, float b) {
    unsigned ua = __float_as_uint(a), ub = __float_as_uint(b);
    return ((ua + 0x8000u) >> 16) | ((ub + 0x8000u) & 0xFFFF0000u);
}
__device__ __forceinline__ unsigned packh2(float a, float b) {
    return __builtin_bit_cast(unsigned, __builtin_amdgcn_cvt_pkrtz(a, b));
}
__device__ __forceinline__ ushort_t f2h(float f) {
    return (ushort_t)(packh2(f, f) & 0xFFFFu);
}
__device__ __forceinline__ bf16x8 ldfrag(const ushort_t* p) {
    return __builtin_bit_cast(bf16x8, *(const uint4*)p);
}
__device__ __forceinline__ f16x8 ldfragh(const ushort_t* p) {
    return __builtin_bit_cast(f16x8, *(const uint4*)p);
}
// raw v_exp_f32 (2^x) with compiler-managed hazards; fallback stays correct
__device__ __forceinline__ float exp2_raw(float x) {
#if __has_builtin(__builtin_amdgcn_exp2f)
    return __builtin_amdgcn_exp2f(x);
#else
    return __expf(x * 0.6931471805599453f);
#endif
}
// async global->LDS DMA, 16B per lane; LDS dest = wave-uniform base + lane*16
__device__ __forceinline__ void ldg2lds16(const void* g, void* l) {
    __builtin_amdgcn_global_load_lds(
        (const __attribute__((address_space(1))) void*)g,
        (__attribute__((address_space(3))) void*)l, 16, 0, 0);
}

__global__ void diag_kernel(float* out, float v) {
    if (threadIdx.x == 0 && blockIdx.x == 0) out[0] = v;
}

// ---- GN pass A: per-channel sums. One block per channel (512 blocks).
__global__ __launch_bounds__(256) void gn_sums(const float* __restrict__ x,
                                               float* __restrict__ S,
                                               float* __restrict__ SS) {
    int c = blockIdx.x, t = threadIdx.x;
    const float4* p = (const float4*)(x + (size_t)c * 4096);
    float s = 0.f, ss = 0.f;
    #pragma unroll
    for (int i = 0; i < 4; i++) {
        float4 f = p[i * 256 + t];
        s += f.x + f.y + f.z + f.w;
        ss += f.x * f.x + f.y * f.y + f.z * f.z + f.w * f.w;
    }
    #pragma unroll
    for (int off = 32; off > 0; off >>= 1) {
        s += __shfl_xor(s, off);
        ss += __shfl_xor(ss, off);
    }
    __shared__ float as[4], bs[4];
    int w = t >> 6;
    if ((t & 63) == 0) { as[w] = s; bs[w] = ss; }
    __syncthreads();
    if (t == 0) {
        S[c] = as[0] + as[1] + as[2] + as[3];
        SS[c] = bs[0] + bs[1] + bs[2] + bs[3];
    }
}

// ---- GN pass B: coefficients. 1 block x 512 threads (thread = channel).
__global__ __launch_bounds__(512) void gn_coef(const float* __restrict__ S,
                                               const float* __restrict__ SS,
                                               const float* __restrict__ gnw,
                                               const float* __restrict__ gnb,
                                               float* __restrict__ qa,
                                               float* __restrict__ qd,
                                               float* __restrict__ va,
                                               float* __restrict__ vd) {
    int c = threadIdx.x;
    float Sc = S[c], SSc = SS[c];
    float gs = Sc, gss = SSc;
    #pragma unroll
    for (int off = 1; off < 16; off <<= 1) {
        gs += __shfl_xor(gs, off);
        gss += __shfl_xor(gss, off);
    }
    float mu = gs * (1.f / GSIZE);
    float var = gss * (1.f / GSIZE) - mu * mu;
    float r1 = rsqrtf(var + 1e-6f);
    float wc = gnw[c], bc = gnb[c];
    float a1 = r1 * wc;
    float d1 = bc - mu * a1;
    qa[c] = a1; qd[c] = d1;
    float S2 = a1 * Sc + 4096.f * d1;
    float SS2 = a1 * a1 * SSc + 2.f * a1 * d1 * Sc + 4096.f * d1 * d1;
    float gs2 = S2, gss2 = SS2;
    #pragma unroll
    for (int off = 1; off < 16; off <<= 1) {
        gs2 += __shfl_xor(gs2, off);
        gss2 += __shfl_xor(gss2, off);
    }
    float mu2 = gs2 * (1.f / GSIZE);
    float var2 = gss2 * (1.f / GSIZE) - mu2 * mu2;
    float r2 = rsqrtf(var2 + 1e-6f);
    float a2 = r2 * wc;
    va[c] = a1 * a2;
    vd[c] = a2 * (d1 - mu2) + bc;
}

// ---- Fused prep: blocks 0..383 = bias_fold; blocks 384..1407 = wprep.
__global__ __launch_bounds__(256) void prep_all(const float* __restrict__ wq,
                                                const float* __restrict__ wk,
                                                const float* __restrict__ wv,
                                                const float* __restrict__ wo,
                                                const float* __restrict__ bq,
                                                const float* __restrict__ bk,
                                                const float* __restrict__ bv,
                                                const float* __restrict__ qa,
                                                const float* __restrict__ qd,
                                                const float* __restrict__ va,
                                                const float* __restrict__ vd,
                                                float* __restrict__ bqf,
                                                float* __restrict__ bkf,
                                                float* __restrict__ bvf,
                                                ushort_t* __restrict__ Wb) {
    int bx = blockIdx.x;
    if (bx < 384) {   // bias fold: b'[o] = b[o] + sum_c W[o][c]*d[c]
        int row = bx * 4 + (threadIdx.x >> 6);   // 0..1535
        int lane = threadIdx.x & 63;
        int m = row >> 9;
        int o = row & 511;
        const float* W = (m == 0) ? wq : (m == 1) ? wk : wv;
        const float* b = (m == 0) ? bq : (m == 1) ? bk : bv;
        const float* d = (m == 0) ? qd : vd;
        float* outp    = (m == 0) ? bqf : (m == 1) ? bkf : bvf;
        const float4* wr = (const float4*)(W + (size_t)o * 512) + lane * 2;
        const float4* dr = (const float4*)d + lane * 2;
        float4 a0 = wr[0], a1 = wr[1], d0 = dr[0], d1 = dr[1];
        float acc = a0.x * d0.x + a0.y * d0.y + a0.z * d0.z + a0.w * d0.w
                  + a1.x * d1.x + a1.y * d1.y + a1.z * d1.z + a1.w * d1.w;
        #pragma unroll
        for (int off = 32; off > 0; off >>= 1) acc += __shfl_xor(acc, off);
        if (lane == 0) outp[o] = b[o] + acc;
    } else {          // weight prep: fp32 -> bf16, GN affine folded
        int idx = bx - 384;                      // 0..1023
        int y = idx >> 8;
        const float* src = (y == 0) ? wq : (y == 1) ? wk : (y == 2) ? wv : wo;
        int i = ((idx & 255) * 256 + threadIdx.x) * 4;
        float4 f = *(const float4*)(src + i);
        if (y < 3) {
            const float* aff = (y == 0) ? qa : va;
            float4 a = *(const float4*)(aff + (i & 511));
            f.x *= a.x; f.y *= a.y; f.z *= a.z; f.w *= a.w;
        }
        uint2 u;
        u.x = pack2r(f.x, f.y);
        u.y = pack2r(f.z, f.w);
        *(uint2*)(Wb + (size_t)y * 262144 + i) = u;
    }
}

// ---- QKV projection. Tile 128m x 64n, K-step 64, grid (64, 12).
__global__ __launch_bounds__(256) void qkv_mfma(const float* __restrict__ x,
                                                const ushort_t* __restrict__ Wb,
                                                const float* __restrict__ bqf,
                                                const float* __restrict__ bkf,
                                                const float* __restrict__ bvf,
                                                ushort_t* __restrict__ QT,
                                                ushort_t* __restrict__ KT,
                                                ushort_t* __restrict__ Vb) {
    __shared__ __align__(16) ushort_t Wl[128][72];
    __shared__ __align__(16) ushort_t Bn[64][72];
    __shared__ __align__(16) ushort_t Tl[64][136];
    int t = threadIdx.x;
    int nbase = blockIdx.x << 6;
    int y = blockIdx.y;
    int buf = y >> 2;
    int obase = (y & 3) << 7;
    const ushort_t* Wsrc = Wb + (size_t)buf * 262144;
    const float* bias = (buf == 0) ? bqf : (buf == 1) ? bkf : bvf;

    int w = t >> 6, lane = t & 63, q15 = lane & 15, quad = lane >> 4;
    f32x4 acc[2][4];
    #pragma unroll
    for (int i = 0; i < 2; i++)
        #pragma unroll
        for (int j = 0; j < 4; j++) acc[i][j] = (f32x4){0.f, 0.f, 0.f, 0.f};

    int tok = t & 63, c8 = t >> 6;         // B staging roles
    for (int ck = 0; ck < 512; ck += 64) {
        __syncthreads();
        #pragma unroll
        for (int i = 0; i < 4; i++) {      // A: 1024 uint4 = 128 rows x 64 k
            int idx = 4 * t + i;
            int row = idx >> 3, seg = idx & 7;
            *(uint4*)&Wl[row][seg * 8] =
                *(const uint4*)&Wsrc[(size_t)(obase + row) * 512 + ck + seg * 8];
        }
        {   // B: 64 tok x 64 chans; lane = tok (coalesced), 16 chans each
            float v[16];
            #pragma unroll
            for (int i = 0; i < 16; i++)
                v[i] = x[(size_t)(ck + c8 * 16 + i) * NTOK + nbase + tok];
            uint4 u0, u1;
            u0.x = pack2r(v[0], v[1]);   u0.y = pack2r(v[2], v[3]);
            u0.z = pack2r(v[4], v[5]);   u0.w = pack2r(v[6], v[7]);
            u1.x = pack2r(v[8], v[9]);   u1.y = pack2r(v[10], v[11]);
            u1.z = pack2r(v[12], v[13]); u1.w = pack2r(v[14], v[15]);
            *(uint4*)&Bn[tok][c8 * 16] = u0;
            *(uint4*)&Bn[tok][c8 * 16 + 8] = u1;
        }
        __syncthreads();
        #pragma unroll
        for (int kk = 0; kk < 2; kk++) {
            bf16x8 af0 = ldfrag(&Wl[w * 32 + q15][kk * 32 + quad * 8]);
            bf16x8 af1 = ldfrag(&Wl[w * 32 + 16 + q15][kk * 32 + quad * 8]);
            #pragma unroll
            for (int n8 = 0; n8 < 4; n8++) {
                bf16x8 bfv = ldfrag(&Bn[n8 * 16 + q15][kk * 32 + quad * 8]);
                acc[0][n8] = __builtin_amdgcn_mfma_f32_16x16x32_bf16(af0, bfv, acc[0][n8], 0, 0, 0);
                acc[1][n8] = __builtin_amdgcn_mfma_f32_16x16x32_bf16(af1, bfv, acc[1][n8], 0, 0, 0);
            }
        }
    }

    if (buf == 2) {   // V: f16 [chan][tok]
        #pragma unroll
        for (int mi = 0; mi < 2; mi++)
            #pragma unroll
            for (int r = 0; r < 4; r++) {
                int o = obase + w * 32 + mi * 16 + quad * 4 + r;
                float bo = bias[o];
                #pragma unroll
                for (int n8 = 0; n8 < 4; n8++)
                    Vb[(size_t)o * NTOK + nbase + n8 * 16 + q15] = f2h(acc[mi][n8][r] + bo);
            }
        return;
    }

    // Q/K: transpose via Tl, full 1024-uint4 flush. Q carries SCALEX (2^x attn).
    ushort_t* dstT = (buf == 0) ? QT : KT;
    float qs = (buf == 0) ? SCALEX : 1.0f;
    __syncthreads();
    #pragma unroll
    for (int mi = 0; mi < 2; mi++)
        #pragma unroll
        for (int r = 0; r < 4; r++) {
            int mloc = w * 32 + mi * 16 + quad * 4 + r;
            float bo = bias[obase + mloc];
            #pragma unroll
            for (int n8 = 0; n8 < 4; n8++)
                Tl[n8 * 16 + q15][mloc] = f2b((acc[mi][n8][r] + bo) * qs);
        }
    __syncthreads();
    #pragma unroll
    for (int i = 0; i < 4; i++) {
        int idx = 4 * t + i;                // 1024 uint4: 64 rows x 16 segs
        int row = idx >> 4, ch = idx & 15;
        uint4 u = *(const uint4*)&Tl[row][ch * 8];
        *(uint4*)&dstT[(size_t)(nbase + row) * 512 + obase + ch * 8] = u;
    }
}

// ---- Attention v15: v14 + software-pipelined h2 (att[2]-style, T15):
// two score buffers; QK MFMAs for h2+1 issue BEFORE exp/pack/PV of h2 so
// the trans-pipe exps overlap the matrix-pipe MFMAs within each wave
// (waves leave the tile barrier phase-locked; per-wave ILP is the only
// way to co-fill both pipes). All stq indices compile-time (full unroll).
__global__ __launch_bounds__(512, 4) void attn_v15(ushort_t* __restrict__ QT,
                                                   const ushort_t* __restrict__ KT,
                                                   const ushort_t* __restrict__ V) {
    __shared__ __align__(16) ushort_t KtF[2][8192];  // [buf][256 keys x 4 gran x 8] swz
    __shared__ __align__(16) ushort_t VtF[2][8192];  // [buf][32 d x 32 gran x 8] swz
    int h = blockIdx.y;
    int t = threadIdx.x;
    int w = t >> 6, lane = t & 63, q15 = lane & 15, quad = lane >> 4;
    int qbase = (blockIdx.x << 7) + w * 16;          // wave-private 16 queries
    int hc = h * 32;
    const ushort_t* Vh = V + (size_t)hc * NTOK;

    bf16x8 qf = ldfrag(&QT[(size_t)(qbase + q15) * 512 + hc + quad * 8]);

    const uint4 onesu = {0x3C003C00u, 0x3C003C00u, 0x3C003C00u, 0x3C003C00u};
    const f16x8 ones = __builtin_bit_cast(f16x8, onesu);

    f32x4 o[2] = {{0.f, 0.f, 0.f, 0.f}, {0.f, 0.f, 0.f, 0.f}};
    f32x4 lacc = {0.f, 0.f, 0.f, 0.f};

    auto issue = [&](int j0, int b) {
        #pragma unroll
        for (int i = 0; i < 2; i++) {      // K: 1024 slots
            int sbase = (w << 6) + (i << 9);
            int idx = sbase + lane;
            int krow = idx >> 2;
            int gd = (idx & 3) ^ ((krow >> 1) & 3);
            int rp = krow & 63;            // key permutation (register-direct P)
            int srcr = (krow & 192) | (rp & 0x23) | ((rp & 0x0C) << 1) | ((rp & 0x10) >> 2);
            ldg2lds16(&KT[(size_t)(j0 + srcr) * 512 + hc + gd * 8],
                      &KtF[b][sbase * 8]);
        }
        #pragma unroll
        for (int i = 0; i < 2; i++) {      // V: 1024 slots
            int sbase = (w << 6) + (i << 9);
            int idx = sbase + lane;
            int d = idx >> 5;
            int gd = (idx & 31) ^ (d & 7);
            ldg2lds16(&Vh[(size_t)d * NTOK + j0 + gd * 8],
                      &VtF[b][sbase * 8]);
        }
    };

    issue(0, 0);
    int ksp8 = (quad ^ ((q15 >> 1) & 3)) * 8;   // K read granule offset (swz)
    int vq = q15 & 7;                           // V read swz key

    for (int tt = 0; tt < 16; tt++) {
        int cur = tt & 1;
        __syncthreads();                   // drains DMA for buf[cur]
        if (tt < 15) issue((tt + 1) << 8, cur ^ 1);
        const ushort_t* KtC = KtF[cur];
        const ushort_t* VtC = VtF[cur];

        f32x4 stq[2][4];
        // prologue: QK for h2 = 0
        __builtin_amdgcn_s_setprio(1);
        #pragma unroll
        for (int kt = 0; kt < 4; kt++) {
            bf16x8 kf = ldfrag(&KtC[(kt * 16 + q15) * 32 + ksp8]);
            f32x4 z = {0.f, 0.f, 0.f, 0.f};
            stq[0][kt] = __builtin_amdgcn_mfma_f32_16x16x32_bf16(kf, qf, z, 0, 0, 0);
        }
        __builtin_amdgcn_s_setprio(0);

        #pragma unroll
        for (int h2 = 0; h2 < 4; h2++) {   // pipelined 64-key sub-passes
            const int c = h2 & 1, n = c ^ 1;
            if (h2 < 3) {                  // QK for h2+1: independent MFMAs
                __builtin_amdgcn_s_setprio(1);
                #pragma unroll
                for (int kt = 0; kt < 4; kt++) {
                    bf16x8 kf = ldfrag(&KtC[((h2 + 1) * 64 + kt * 16 + q15) * 32 + ksp8]);
                    f32x4 z = {0.f, 0.f, 0.f, 0.f};
                    stq[n][kt] = __builtin_amdgcn_mfma_f32_16x16x32_bf16(kf, qf, z, 0, 0, 0);
                }
                __builtin_amdgcn_s_setprio(0);
            }

            // V fragments for current h2 (independent of QK-next)
            int g0 = ((h2 * 8 + quad) ^ vq) * 8;
            int g1 = g0 ^ 32;              // (x^4)*8 == (x*8)^32 for quad<4
            f16x8 v00 = ldfragh(&VtC[q15 * 256 + g0]);
            f16x8 v01 = ldfragh(&VtC[(16 + q15) * 256 + g0]);
            f16x8 v10 = ldfragh(&VtC[q15 * 256 + g1]);
            f16x8 v11 = ldfragh(&VtC[(16 + q15) * 256 + g1]);

            // exp current (trans pipe — overlaps QK-next on the MFMA pipe)
            #pragma unroll
            for (int kt = 0; kt < 4; kt++)
                #pragma unroll
                for (int r = 0; r < 4; r++)
                    stq[c][kt][r] = exp2_raw(stq[c][kt][r]);

            uint4 p0u;
            p0u.x = packh2(stq[c][0][0], stq[c][0][1]);
            p0u.y = packh2(stq[c][0][2], stq[c][0][3]);
            p0u.z = packh2(stq[c][1][0], stq[c][1][1]);
            p0u.w = packh2(stq[c][1][2], stq[c][1][3]);
            f16x8 pf0 = __builtin_bit_cast(f16x8, p0u);
            __builtin_amdgcn_s_setprio(1);
            o[0] = __builtin_amdgcn_mfma_f32_16x16x32_f16(pf0, v00, o[0], 0, 0, 0);
            o[1] = __builtin_amdgcn_mfma_f32_16x16x32_f16(pf0, v01, o[1], 0, 0, 0);
            lacc = __builtin_amdgcn_mfma_f32_16x16x32_f16(pf0, ones, lacc, 0, 0, 0);
            __builtin_amdgcn_s_setprio(0);
            uint4 p1u;                     // pack of 2nd half overlaps PV(pf0)
            p1u.x = packh2(stq[c][2][0], stq[c][2][1]);
            p1u.y = packh2(stq[c][2][2], stq[c][2][3]);
            p1u.z = packh2(stq[c][3][0], stq[c][3][1]);
            p1u.w = packh2(stq[c][3][2], stq[c][3][3]);
            f16x8 pf1 = __builtin_bit_cast(f16x8, p1u);
            __builtin_amdgcn_s_setprio(1);
            o[0] = __builtin_amdgcn_mfma_f32_16x16x32_f16(pf1, v10, o[0], 0, 0, 0);
            o[1] = __builtin_amdgcn_mfma_f32_16x16x32_f16(pf1, v11, o[1], 0, 0, 0);
            lacc = __builtin_amdgcn_mfma_f32_16x16x32_f16(pf1, ones, lacc, 0, 0, 0);
            __builtin_amdgcn_s_setprio(0);
        }
    }

    #pragma unroll
    for (int r = 0; r < 4; r++) {
        float li = 1.f / lacc[r];
        int q = quad * 4 + r;
        QT[(size_t)(qbase + q) * 512 + hc + q15]      = f2b(o[0][r] * li);
        QT[(size_t)(qbase + q) * 512 + hc + 16 + q15] = f2b(o[1][r] * li);
    }
}

// ---- Output projection: tile 64m x 64n, K-step 64 (8 staged steps), grid (64, 8).
__global__ __launch_bounds__(256) void oproj_mfma(const ushort_t* __restrict__ OT,
                                                  const ushort_t* __restrict__ Wob,
                                                  const float* __restrict__ bo,
                                                  const float* __restrict__ x,
                                                  float* __restrict__ out) {
    __shared__ __align__(16) ushort_t Wl[64][72];
    __shared__ __align__(16) ushort_t Bn[64][72];
    int t = threadIdx.x;
    int nbase = blockIdx.x << 6;
    int obase = blockIdx.y << 6;
    int w = t >> 6, lane = t & 63, q15 = lane & 15, quad = lane >> 4;

    f32x4 acc[4];
    #pragma unroll
    for (int i = 0; i < 4; i++) acc[i] = (f32x4){0.f, 0.f, 0.f, 0.f};

    for (int ck = 0; ck < 512; ck += 64) {
        __syncthreads();
        #pragma unroll
        for (int i = 0; i < 2; i++) {      // 512 uint4 per tile, 2 per thread
            int idx = t * 2 + i;
            int row = idx >> 3, seg = idx & 7;
            *(uint4*)&Wl[row][seg * 8] =
                *(const uint4*)&Wob[(size_t)(obase + row) * 512 + ck + seg * 8];
            *(uint4*)&Bn[row][seg * 8] =
                *(const uint4*)&OT[(size_t)(nbase + row) * 512 + ck + seg * 8];
        }
        __syncthreads();
        #pragma unroll
        for (int kk = 0; kk < 2; kk++) {
            bf16x8 af = ldfrag(&Wl[w * 16 + q15][kk * 32 + quad * 8]);
            #pragma unroll
            for (int n8 = 0; n8 < 4; n8++) {
                bf16x8 bfv = ldfrag(&Bn[n8 * 16 + q15][kk * 32 + quad * 8]);
                acc[n8] = __builtin_amdgcn_mfma_f32_16x16x32_bf16(af, bfv, acc[n8], 0, 0, 0);
            }
        }
    }

    #pragma unroll
    for (int r = 0; r < 4; r++) {
        int o = obase + w * 16 + quad * 4 + r;
        float b = bo[o];
        #pragma unroll
        for (int n8 = 0; n8 < 4; n8++) {
            size_t idx = (size_t)o * NTOK + nbase + n8 * 16 + q15;
            out[idx] = (acc[n8][r] + b + x[idx]) * RSQRT2;
        }
    }
}

extern "C" void kernel_launch(void* const* d_in, const int* in_sizes, int n_in,
                              void* d_out, int out_size, void* d_ws, size_t ws_size,
                              hipStream_t stream) {
    const float* x   = (const float*)d_in[0];
    const float* gnw = (const float*)d_in[1];
    const float* gnb = (const float*)d_in[2];
    const float* wq  = (const float*)d_in[3];
    const float* bq  = (const float*)d_in[4];
    const float* wk  = (const float*)d_in[5];
    const float* bk  = (const float*)d_in[6];
    const float* wv  = (const float*)d_in[7];
    const float* bv  = (const float*)d_in[8];
    const float* wo  = (const float*)d_in[9];
    const float* bo  = (const float*)d_in[10];
    float* out = (float*)d_out;

    if (ws_size < WS_NEEDED) {
        diag_kernel<<<1, 64, 0, stream>>>(out, (float)(ws_size >> 16));
        return;
    }

    char* wsb = (char*)d_ws;
    float* S   = (float*)(wsb + 0);
    float* SS  = (float*)(wsb + 2048);
    float* qa  = (float*)(wsb + 4096);
    float* qd  = (float*)(wsb + 6144);
    float* va  = (float*)(wsb + 8192);
    float* vd  = (float*)(wsb + 10240);
    float* bqf = (float*)(wsb + 12288);
    float* bkf = (float*)(wsb + 14336);
    float* bvf = (float*)(wsb + 16384);
    ushort_t* Wb = (ushort_t*)(wsb + WB_OFF);    // 2 MB bf16 (wq'|wk'|wv'|wo)
    ushort_t* QT = (ushort_t*)(wsb + QT_OFF);    // 4 MB bf16 [4096][512] (becomes O)
    ushort_t* KT = (ushort_t*)d_out;                        // 4 MB bf16 [4096][512]
    ushort_t* Vb = (ushort_t*)d_out + (size_t)CHAN * NTOK;  // 4 MB f16 [512][4096]

    gn_sums<<<512, 256, 0, stream>>>(x, S, SS);
    gn_coef<<<1, 512, 0, stream>>>(S, SS, gnw, gnb, qa, qd, va, vd);
    prep_all<<<1408, 256, 0, stream>>>(wq, wk, wv, wo, bq, bk, bv,
                                       qa, qd, va, vd, bqf, bkf, bvf, Wb);

    qkv_mfma<<<dim3(64, 12), 256, 0, stream>>>(x, Wb, bqf, bkf, bvf, QT, KT, Vb);

    attn_v15<<<dim3(32, 16), 512, 0, stream>>>(QT, KT, Vb);

    oproj_mfma<<<dim3(64, 8), 256, 0, stream>>>(QT, Wb + (size_t)3 * 262144, bo, x, out);
}

// Round 8
// 160.832 us; speedup vs baseline: 1.2178x; 1.0054x over previous
//
#include <hip/hip_runtime.h>

#define NTOK 4096
#define CHAN 512
#define GSIZE 65536
#define RSQRT2 0.7071067811865476f
#define SCALEX 0.2550348837f        // (1/sqrt(32)) * log2(e); attn uses raw 2^x
#define WB_OFF 32768
#define QT_OFF (WB_OFF + 2097152)
#define XT_OFF (QT_OFF + 4194304)
#define WS_NEEDED ((size_t)(XT_OFF + 4194304))

typedef unsigned short ushort_t;
typedef __attribute__((ext_vector_type(8))) short bf16x8;
typedef __attribute__((ext_vector_type(8))) _Float16 f16x8;
typedef __attribute__((ext_vector_type(4))) float f32x4;

__device__ __forceinline__ ushort_t f2b(float f) {
    unsigned u = __float_as_uint(f);
    unsigned r = (u + 0x7FFFu + ((u >> 16) & 1u)) >> 16;
    return (ushort_t)r;
}
__device__ __forceinline__ unsigned pack2r(float a, float b) {
    unsigned ua = __float_as_uint(a), ub = __float_as_uint(b);
    return ((ua + 0x8000u) >> 16) | ((ub + 0x8000u) & 0xFFFF0000u);
}
__device__ __forceinline__ unsigned packh2(float a, float b) {
    return __builtin_bit_cast(unsigned, __builtin_amdgcn_cvt_pkrtz(a, b));
}
__device__ __forceinline__ ushort_t f2h(float f) {
    return (ushort_t)(packh2(f, f) & 0xFFFFu);
}
__device__ __forceinline__ bf16x8 ldfrag(const ushort_t* p) {
    return __builtin_bit_cast(bf16x8, *(const uint4*)p);
}
__device__ __forceinline__ f16x8 ldfragh(const ushort_t* p) {
    return __builtin_bit_cast(f16x8, *(const uint4*)p);
}
// raw v_exp_f32 (2^x) with compiler-managed hazards; fallback stays correct
__device__ __forceinline__ float exp2_raw(float x) {
#if __has_builtin(__builtin_amdgcn_exp2f)
    return __builtin_amdgcn_exp2f(x);
#else
    return __expf(x * 0.6931471805599453f);
#endif
}
// async global->LDS DMA, 16B per lane; LDS dest = wave-uniform base + lane*16
__device__ __forceinline__ void ldg2lds16(const void* g, void* l) {
    __builtin_amdgcn_global_load_lds(
        (const __attribute__((address_space(1))) void*)g,
        (__attribute__((address_space(3))) void*)l, 16, 0, 0);
}

__global__ void diag_kernel(float* out, float v) {
    if (threadIdx.x == 0 && blockIdx.x == 0) out[0] = v;
}

// ---- GN pass A: per-channel sums. One block per channel (512 blocks).
__global__ __launch_bounds__(256) void gn_sums(const float* __restrict__ x,
                                               float* __restrict__ S,
                                               float* __restrict__ SS) {
    int c = blockIdx.x, t = threadIdx.x;
    const float4* p = (const float4*)(x + (size_t)c * 4096);
    float s = 0.f, ss = 0.f;
    #pragma unroll
    for (int i = 0; i < 4; i++) {
        float4 f = p[i * 256 + t];
        s += f.x + f.y + f.z + f.w;
        ss += f.x * f.x + f.y * f.y + f.z * f.z + f.w * f.w;
    }
    #pragma unroll
    for (int off = 32; off > 0; off >>= 1) {
        s += __shfl_xor(s, off);
        ss += __shfl_xor(ss, off);
    }
    __shared__ float as[4], bs[4];
    int w = t >> 6;
    if ((t & 63) == 0) { as[w] = s; bs[w] = ss; }
    __syncthreads();
    if (t == 0) {
        S[c] = as[0] + as[1] + as[2] + as[3];
        SS[c] = bs[0] + bs[1] + bs[2] + bs[3];
    }
}

// ---- GN pass B: coefficients. 1 block x 512 threads (thread = channel).
__global__ __launch_bounds__(512) void gn_coef(const float* __restrict__ S,
                                               const float* __restrict__ SS,
                                               const float* __restrict__ gnw,
                                               const float* __restrict__ gnb,
                                               float* __restrict__ qa,
                                               float* __restrict__ qd,
                                               float* __restrict__ va,
                                               float* __restrict__ vd) {
    int c = threadIdx.x;
    float Sc = S[c], SSc = SS[c];
    float gs = Sc, gss = SSc;
    #pragma unroll
    for (int off = 1; off < 16; off <<= 1) {
        gs += __shfl_xor(gs, off);
        gss += __shfl_xor(gss, off);
    }
    float mu = gs * (1.f / GSIZE);
    float var = gss * (1.f / GSIZE) - mu * mu;
    float r1 = rsqrtf(var + 1e-6f);
    float wc = gnw[c], bc = gnb[c];
    float a1 = r1 * wc;
    float d1 = bc - mu * a1;
    qa[c] = a1; qd[c] = d1;
    float S2 = a1 * Sc + 4096.f * d1;
    float SS2 = a1 * a1 * SSc + 2.f * a1 * d1 * Sc + 4096.f * d1 * d1;
    float gs2 = S2, gss2 = SS2;
    #pragma unroll
    for (int off = 1; off < 16; off <<= 1) {
        gs2 += __shfl_xor(gs2, off);
        gss2 += __shfl_xor(gss2, off);
    }
    float mu2 = gs2 * (1.f / GSIZE);
    float var2 = gss2 * (1.f / GSIZE) - mu2 * mu2;
    float r2 = rsqrtf(var2 + 1e-6f);
    float a2 = r2 * wc;
    va[c] = a1 * a2;
    vd[c] = a2 * (d1 - mu2) + bc;
}

// ---- Fused prep: blocks 0..383 = bias_fold; blocks 384..1407 = wprep.
__global__ __launch_bounds__(256) void prep_all(const float* __restrict__ wq,
                                                const float* __restrict__ wk,
                                                const float* __restrict__ wv,
                                                const float* __restrict__ wo,
                                                const float* __restrict__ bq,
                                                const float* __restrict__ bk,
                                                const float* __restrict__ bv,
                                                const float* __restrict__ qa,
                                                const float* __restrict__ qd,
                                                const float* __restrict__ va,
                                                const float* __restrict__ vd,
                                                float* __restrict__ bqf,
                                                float* __restrict__ bkf,
                                                float* __restrict__ bvf,
                                                ushort_t* __restrict__ Wb) {
    int bx = blockIdx.x;
    if (bx < 384) {   // bias fold: b'[o] = b[o] + sum_c W[o][c]*d[c]
        int row = bx * 4 + (threadIdx.x >> 6);   // 0..1535
        int lane = threadIdx.x & 63;
        int m = row >> 9;
        int o = row & 511;
        const float* W = (m == 0) ? wq : (m == 1) ? wk : wv;
        const float* b = (m == 0) ? bq : (m == 1) ? bk : bv;
        const float* d = (m == 0) ? qd : vd;
        float* outp    = (m == 0) ? bqf : (m == 1) ? bkf : bvf;
        const float4* wr = (const float4*)(W + (size_t)o * 512) + lane * 2;
        const float4* dr = (const float4*)d + lane * 2;
        float4 a0 = wr[0], a1 = wr[1], d0 = dr[0], d1 = dr[1];
        float acc = a0.x * d0.x + a0.y * d0.y + a0.z * d0.z + a0.w * d0.w
                  + a1.x * d1.x + a1.y * d1.y + a1.z * d1.z + a1.w * d1.w;
        #pragma unroll
        for (int off = 32; off > 0; off >>= 1) acc += __shfl_xor(acc, off);
        if (lane == 0) outp[o] = b[o] + acc;
    } else {          // weight prep: fp32 -> bf16, GN affine folded
        int idx = bx - 384;                      // 0..1023
        int y = idx >> 8;
        const float* src = (y == 0) ? wq : (y == 1) ? wk : (y == 2) ? wv : wo;
        int i = ((idx & 255) * 256 + threadIdx.x) * 4;
        float4 f = *(const float4*)(src + i);
        if (y < 3) {
            const float* aff = (y == 0) ? qa : va;
            float4 a = *(const float4*)(aff + (i & 511));
            f.x *= a.x; f.y *= a.y; f.z *= a.z; f.w *= a.w;
        }
        uint2 u;
        u.x = pack2r(f.x, f.y);
        u.y = pack2r(f.z, f.w);
        *(uint2*)(Wb + (size_t)y * 262144 + i) = u;
    }
}

// ---- x transpose + bf16 convert, once: x [512 chan][4096 tok] fp32 ->
// xT [4096 tok][512 chan] bf16. Same pack2r rounding as the old in-kernel
// conversion -> bit-identical MFMA inputs. Grid 512 x 256.
__global__ __launch_bounds__(256) void xprep(const float* __restrict__ x,
                                             ushort_t* __restrict__ xT) {
    int bx = blockIdx.x;
    int t0 = (bx & 63) << 6;        // token base
    int c0 = (bx >> 6) << 6;        // channel base
    int t = threadIdx.x;
    int tok = t & 63, c16 = t >> 6; // thread: one token, 16 channels
    float v[16];
    #pragma unroll
    for (int i = 0; i < 16; i++)
        v[i] = x[(size_t)(c0 + c16 * 16 + i) * NTOK + t0 + tok];
    uint4 u0, u1;
    u0.x = pack2r(v[0], v[1]);   u0.y = pack2r(v[2], v[3]);
    u0.z = pack2r(v[4], v[5]);   u0.w = pack2r(v[6], v[7]);
    u1.x = pack2r(v[8], v[9]);   u1.y = pack2r(v[10], v[11]);
    u1.z = pack2r(v[12], v[13]); u1.w = pack2r(v[14], v[15]);
    ushort_t* dst = xT + (size_t)(t0 + tok) * 512 + c0 + c16 * 16;
    *(uint4*)dst = u0;
    *(uint4*)(dst + 8) = u1;
}

// ---- QKV projection v2: both operands DMA-staged (global_load_lds) from
// bf16 sources, double-buffered, one barrier per K-step. Source granules
// XOR-swizzled (g ^ row&7) so fragment ds_read_b128 is 2-way (free).
// LDS 48KB (staging) with Tl epilogue overlaid -> 3 blocks/CU.
__global__ __launch_bounds__(256) void qkv_mfma(const ushort_t* __restrict__ xT,
                                                const ushort_t* __restrict__ Wb,
                                                const float* __restrict__ bqf,
                                                const float* __restrict__ bkf,
                                                const float* __restrict__ bvf,
                                                ushort_t* __restrict__ QT,
                                                ushort_t* __restrict__ KT,
                                                ushort_t* __restrict__ Vb) {
    __shared__ __align__(16) ushort_t SH[2][12288];  // [buf][Wl 8192 | Bn 4096]
    int t = threadIdx.x;
    int nbase = blockIdx.x << 6;
    int y = blockIdx.y;
    int buf = y >> 2;
    int obase = (y & 3) << 7;
    const ushort_t* Wsrc = Wb + (size_t)buf * 262144 + (size_t)obase * 512;
    const float* bias = (buf == 0) ? bqf : (buf == 1) ? bkf : bvf;

    int w = t >> 6, lane = t & 63, q15 = lane & 15, quad = lane >> 4;
    f32x4 acc[2][4];
    #pragma unroll
    for (int i = 0; i < 2; i++)
        #pragma unroll
        for (int j = 0; j < 4; j++) acc[i][j] = (f32x4){0.f, 0.f, 0.f, 0.f};

    auto issue = [&](int ck, int b) {
        ushort_t* base = SH[b];
        #pragma unroll
        for (int i = 0; i < 4; i++) {       // A: 128 rows x 8 granules
            int idx = t + (i << 8);
            int row = idx >> 3, gs = idx & 7;
            int g = gs ^ (row & 7);
            ldg2lds16(&Wsrc[(size_t)row * 512 + ck + g * 8], &base[idx * 8]);
        }
        #pragma unroll
        for (int i = 0; i < 2; i++) {       // B: 64 toks x 8 granules
            int idx = t + (i << 8);
            int tok = idx >> 3, gs = idx & 7;
            int g = gs ^ (tok & 7);
            ldg2lds16(&xT[(size_t)(nbase + tok) * 512 + ck + g * 8],
                      &base[8192 + idx * 8]);
        }
    };

    issue(0, 0);
    int swz = q15 & 7;
    for (int s = 0; s < 8; s++) {
        int cur = s & 1;
        __syncthreads();                    // drains DMA for buf[cur]
        if (s < 7) issue((s + 1) * 64, cur ^ 1);
        const ushort_t* Wl = SH[cur];
        const ushort_t* Bn = SH[cur] + 8192;
        #pragma unroll
        for (int kk = 0; kk < 2; kk++) {
            int g = (kk * 4 + quad) ^ swz;
            bf16x8 af0 = ldfrag(&Wl[((w * 32 + q15) * 8 + g) * 8]);
            bf16x8 af1 = ldfrag(&Wl[((w * 32 + 16 + q15) * 8 + g) * 8]);
            #pragma unroll
            for (int n8 = 0; n8 < 4; n8++) {
                bf16x8 bfv = ldfrag(&Bn[((n8 * 16 + q15) * 8 + g) * 8]);
                acc[0][n8] = __builtin_amdgcn_mfma_f32_16x16x32_bf16(af0, bfv, acc[0][n8], 0, 0, 0);
                acc[1][n8] = __builtin_amdgcn_mfma_f32_16x16x32_bf16(af1, bfv, acc[1][n8], 0, 0, 0);
            }
        }
    }

    if (buf == 2) {   // V: f16 [chan][tok]
        #pragma unroll
        for (int mi = 0; mi < 2; mi++)
            #pragma unroll
            for (int r = 0; r < 4; r++) {
                int o = obase + w * 32 + mi * 16 + quad * 4 + r;
                float bo = bias[o];
                #pragma unroll
                for (int n8 = 0; n8 < 4; n8++)
                    Vb[(size_t)o * NTOK + nbase + n8 * 16 + q15] = f2h(acc[mi][n8][r] + bo);
            }
        return;
    }

    // Q/K: transpose via Tl (overlaid on SH[0]; stride 136), full flush.
    ushort_t* Tl = SH[0];
    __syncthreads();                        // all waves done with SH reads
    float qs = (buf == 0) ? SCALEX : 1.0f;
    #pragma unroll
    for (int mi = 0; mi < 2; mi++)
        #pragma unroll
        for (int r = 0; r < 4; r++) {
            int mloc = w * 32 + mi * 16 + quad * 4 + r;
            float bo = bias[obase + mloc];
            #pragma unroll
            for (int n8 = 0; n8 < 4; n8++)
                Tl[(n8 * 16 + q15) * 136 + mloc] = f2b((acc[mi][n8][r] + bo) * qs);
        }
    __syncthreads();
    ushort_t* dstT = (buf == 0) ? QT : KT;
    #pragma unroll
    for (int i = 0; i < 4; i++) {
        int idx = 4 * t + i;                // 1024 uint4: 64 rows x 16 segs
        int row = idx >> 4, ch = idx & 15;
        uint4 u = *(const uint4*)&Tl[row * 136 + ch * 8];
        *(uint4*)&dstT[(size_t)(nbase + row) * 512 + obase + ch * 8] = u;
    }
}

// ---- Attention v14 (proven 53.9 us): register-direct P via key permutation,
// DMA double-buffer, source swizzle, raw v_exp_f32 (log2e folded into Q).
__global__ __launch_bounds__(512, 4) void attn_v14(ushort_t* __restrict__ QT,
                                                   const ushort_t* __restrict__ KT,
                                                   const ushort_t* __restrict__ V) {
    __shared__ __align__(16) ushort_t KtF[2][8192];  // [buf][256 keys x 4 gran x 8] swz
    __shared__ __align__(16) ushort_t VtF[2][8192];  // [buf][32 d x 32 gran x 8] swz
    int h = blockIdx.y;
    int t = threadIdx.x;
    int w = t >> 6, lane = t & 63, q15 = lane & 15, quad = lane >> 4;
    int qbase = (blockIdx.x << 7) + w * 16;          // wave-private 16 queries
    int hc = h * 32;
    const ushort_t* Vh = V + (size_t)hc * NTOK;

    bf16x8 qf = ldfrag(&QT[(size_t)(qbase + q15) * 512 + hc + quad * 8]);

    const uint4 onesu = {0x3C003C00u, 0x3C003C00u, 0x3C003C00u, 0x3C003C00u};
    const f16x8 ones = __builtin_bit_cast(f16x8, onesu);

    f32x4 o[2] = {{0.f, 0.f, 0.f, 0.f}, {0.f, 0.f, 0.f, 0.f}};
    f32x4 lacc = {0.f, 0.f, 0.f, 0.f};

    auto issue = [&](int j0, int b) {
        #pragma unroll
        for (int i = 0; i < 2; i++) {      // K: 1024 slots
            int sbase = (w << 6) + (i << 9);
            int idx = sbase + lane;
            int krow = idx >> 2;
            int gd = (idx & 3) ^ ((krow >> 1) & 3);
            int rp = krow & 63;            // key permutation (register-direct P)
            int srcr = (krow & 192) | (rp & 0x23) | ((rp & 0x0C) << 1) | ((rp & 0x10) >> 2);
            ldg2lds16(&KT[(size_t)(j0 + srcr) * 512 + hc + gd * 8],
                      &KtF[b][sbase * 8]);
        }
        #pragma unroll
        for (int i = 0; i < 2; i++) {      // V: 1024 slots
            int sbase = (w << 6) + (i << 9);
            int idx = sbase + lane;
            int d = idx >> 5;
            int gd = (idx & 31) ^ (d & 7);
            ldg2lds16(&Vh[(size_t)d * NTOK + j0 + gd * 8],
                      &VtF[b][sbase * 8]);
        }
    };

    issue(0, 0);
    int ksp8 = (quad ^ ((q15 >> 1) & 3)) * 8;   // K read granule offset (swz)
    int vq = q15 & 7;                           // V read swz key

    for (int tt = 0; tt < 16; tt++) {
        int cur = tt & 1;
        __syncthreads();                   // drains DMA for buf[cur]
        if (tt < 15) issue((tt + 1) << 8, cur ^ 1);
        const ushort_t* KtC = KtF[cur];
        const ushort_t* VtC = VtF[cur];

        #pragma unroll
        for (int h2 = 0; h2 < 4; h2++) {   // four 64-key sub-passes
            f32x4 st[4];
            __builtin_amdgcn_s_setprio(1);
            #pragma unroll
            for (int kt = 0; kt < 4; kt++) {
                bf16x8 kf = ldfrag(&KtC[(h2 * 64 + kt * 16 + q15) * 32 + ksp8]);
                f32x4 z = {0.f, 0.f, 0.f, 0.f};
                st[kt] = __builtin_amdgcn_mfma_f32_16x16x32_bf16(kf, qf, z, 0, 0, 0);
            }
            __builtin_amdgcn_s_setprio(0);

            #pragma unroll
            for (int kt = 0; kt < 4; kt++)
                #pragma unroll
                for (int r = 0; r < 4; r++)
                    st[kt][r] = exp2_raw(st[kt][r]);

            int g0 = ((h2 * 8 + quad) ^ vq) * 8;
            int g1 = g0 ^ 32;              // (x^4)*8 == (x*8)^32 for quad<4
            f16x8 v00 = ldfragh(&VtC[q15 * 256 + g0]);
            f16x8 v01 = ldfragh(&VtC[(16 + q15) * 256 + g0]);
            f16x8 v10 = ldfragh(&VtC[q15 * 256 + g1]);
            f16x8 v11 = ldfragh(&VtC[(16 + q15) * 256 + g1]);

            uint4 p0u, p1u;
            p0u.x = packh2(st[0][0], st[0][1]);
            p0u.y = packh2(st[0][2], st[0][3]);
            p0u.z = packh2(st[1][0], st[1][1]);
            p0u.w = packh2(st[1][2], st[1][3]);
            p1u.x = packh2(st[2][0], st[2][1]);
            p1u.y = packh2(st[2][2], st[2][3]);
            p1u.z = packh2(st[3][0], st[3][1]);
            p1u.w = packh2(st[3][2], st[3][3]);
            f16x8 pf0 = __builtin_bit_cast(f16x8, p0u);
            f16x8 pf1 = __builtin_bit_cast(f16x8, p1u);
            __builtin_amdgcn_s_setprio(1);
            o[0] = __builtin_amdgcn_mfma_f32_16x16x32_f16(pf0, v00, o[0], 0, 0, 0);
            o[1] = __builtin_amdgcn_mfma_f32_16x16x32_f16(pf0, v01, o[1], 0, 0, 0);
            lacc = __builtin_amdgcn_mfma_f32_16x16x32_f16(pf0, ones, lacc, 0, 0, 0);
            o[0] = __builtin_amdgcn_mfma_f32_16x16x32_f16(pf1, v10, o[0], 0, 0, 0);
            o[1] = __builtin_amdgcn_mfma_f32_16x16x32_f16(pf1, v11, o[1], 0, 0, 0);
            lacc = __builtin_amdgcn_mfma_f32_16x16x32_f16(pf1, ones, lacc, 0, 0, 0);
            __builtin_amdgcn_s_setprio(0);
        }
    }

    #pragma unroll
    for (int r = 0; r < 4; r++) {
        float li = 1.f / lacc[r];
        int q = quad * 4 + r;
        QT[(size_t)(qbase + q) * 512 + hc + q15]      = f2b(o[0][r] * li);
        QT[(size_t)(qbase + q) * 512 + hc + 16 + q15] = f2b(o[1][r] * li);
    }
}

// ---- Output projection: tile 64m x 64n, K-step 64 (8 staged steps), grid (64, 8).
__global__ __launch_bounds__(256) void oproj_mfma(const ushort_t* __restrict__ OT,
                                                  const ushort_t* __restrict__ Wob,
                                                  const float* __restrict__ bo,
                                                  const float* __restrict__ x,
                                                  float* __restrict__ out) {
    __shared__ __align__(16) ushort_t Wl[64][72];
    __shared__ __align__(16) ushort_t Bn[64][72];
    int t = threadIdx.x;
    int nbase = blockIdx.x << 6;
    int obase = blockIdx.y << 6;
    int w = t >> 6, lane = t & 63, q15 = lane & 15, quad = lane >> 4;

    f32x4 acc[4];
    #pragma unroll
    for (int i = 0; i < 4; i++) acc[i] = (f32x4){0.f, 0.f, 0.f, 0.f};

    for (int ck = 0; ck < 512; ck += 64) {
        __syncthreads();
        #pragma unroll
        for (int i = 0; i < 2; i++) {      // 512 uint4 per tile, 2 per thread
            int idx = t * 2 + i;
            int row = idx >> 3, seg = idx & 7;
            *(uint4*)&Wl[row][seg * 8] =
                *(const uint4*)&Wob[(size_t)(obase + row) * 512 + ck + seg * 8];
            *(uint4*)&Bn[row][seg * 8] =
                *(const uint4*)&OT[(size_t)(nbase + row) * 512 + ck + seg * 8];
        }
        __syncthreads();
        #pragma unroll
        for (int kk = 0; kk < 2; kk++) {
            bf16x8 af = ldfrag(&Wl[w * 16 + q15][kk * 32 + quad * 8]);
            #pragma unroll
            for (int n8 = 0; n8 < 4; n8++) {
                bf16x8 bfv = ldfrag(&Bn[n8 * 16 + q15][kk * 32 + quad * 8]);
                acc[n8] = __builtin_amdgcn_mfma_f32_16x16x32_bf16(af, bfv, acc[n8], 0, 0, 0);
            }
        }
    }

    #pragma unroll
    for (int r = 0; r < 4; r++) {
        int o = obase + w * 16 + quad * 4 + r;
        float b = bo[o];
        #pragma unroll
        for (int n8 = 0; n8 < 4; n8++) {
            size_t idx = (size_t)o * NTOK + nbase + n8 * 16 + q15;
            out[idx] = (acc[n8][r] + b + x[idx]) * RSQRT2;
        }
    }
}

extern "C" void kernel_launch(void* const* d_in, const int* in_sizes, int n_in,
                              void* d_out, int out_size, void* d_ws, size_t ws_size,
                              hipStream_t stream) {
    const float* x   = (const float*)d_in[0];
    const float* gnw = (const float*)d_in[1];
    const float* gnb = (const float*)d_in[2];
    const float* wq  = (const float*)d_in[3];
    const float* bq  = (const float*)d_in[4];
    const float* wk  = (const float*)d_in[5];
    const float* bk  = (const float*)d_in[6];
    const float* wv  = (const float*)d_in[7];
    const float* bv  = (const float*)d_in[8];
    const float* wo  = (const float*)d_in[9];
    const float* bo  = (const float*)d_in[10];
    float* out = (float*)d_out;

    if (ws_size < WS_NEEDED) {
        diag_kernel<<<1, 64, 0, stream>>>(out, (float)(ws_size >> 16));
        return;
    }

    char* wsb = (char*)d_ws;
    float* S   = (float*)(wsb + 0);
    float* SS  = (float*)(wsb + 2048);
    float* qa  = (float*)(wsb + 4096);
    float* qd  = (float*)(wsb + 6144);
    float* va  = (float*)(wsb + 8192);
    float* vd  = (float*)(wsb + 10240);
    float* bqf = (float*)(wsb + 12288);
    float* bkf = (float*)(wsb + 14336);
    float* bvf = (float*)(wsb + 16384);
    ushort_t* Wb = (ushort_t*)(wsb + WB_OFF);    // 2 MB bf16 (wq'|wk'|wv'|wo)
    ushort_t* QT = (ushort_t*)(wsb + QT_OFF);    // 4 MB bf16 [4096][512] (becomes O)
    ushort_t* xT = (ushort_t*)(wsb + XT_OFF);    // 4 MB bf16 [4096][512] x transposed
    ushort_t* KT = (ushort_t*)d_out;                        // 4 MB bf16 [4096][512]
    ushort_t* Vb = (ushort_t*)d_out + (size_t)CHAN * NTOK;  // 4 MB f16 [512][4096]

    gn_sums<<<512, 256, 0, stream>>>(x, S, SS);
    gn_coef<<<1, 512, 0, stream>>>(S, SS, gnw, gnb, qa, qd, va, vd);
    prep_all<<<1408, 256, 0, stream>>>(wq, wk, wv, wo, bq, bk, bv,
                                       qa, qd, va, vd, bqf, bkf, bvf, Wb);
    xprep<<<512, 256, 0, stream>>>(x, xT);

    qkv_mfma<<<dim3(64, 12), 256, 0, stream>>>(xT, Wb, bqf, bkf, bvf, QT, KT, Vb);

    attn_v14<<<dim3(32, 16), 512, 0, stream>>>(QT, KT, Vb);

    oproj_mfma<<<dim3(64, 8), 256, 0, stream>>>(QT, Wb + (size_t)3 * 262144, bo, x, out);
}